// Round 6
// baseline (360.262 us; speedup 1.0000x reference)
//
#include <hip/hip_runtime.h>
#include <hip/hip_bf16.h>

#define B_  2
#define T_  1024
#define D_  768
#define H_  12
#define NT  2048        // B*T
#define DQ_ 1024
#define PH_ 4
#define NK_ 256
#define TK_ 32
#define DHK_ 128
#define QKVLD 2304      // merged QKV row stride

typedef __attribute__((ext_vector_type(8))) short bf16x8;
typedef __attribute__((ext_vector_type(4))) float f32x4;

static __device__ __forceinline__ unsigned short f2bf(float f) {
    union { float f; unsigned u; } c; c.f = f;
    unsigned r = (c.u + 0x7fffu + ((c.u >> 16) & 1u)) >> 16;
    return (unsigned short)r;
}

static __device__ __forceinline__ float bf2f(unsigned short s) {
    union { unsigned u; float f; } c; c.u = ((unsigned)s) << 16;
    return c.f;
}

// async global->LDS, 16B per lane; lds base must be wave-uniform (HW adds lane*16)
static __device__ __forceinline__ void gload16(const unsigned short* g, unsigned short* l) {
    __builtin_amdgcn_global_load_lds((const __attribute__((address_space(1))) unsigned int*)g,
                                     (__attribute__((address_space(3))) unsigned int*)l, 16, 0, 0);
}

// ---------------- batched transpose+convert: 5 weight matrices in one launch ----------------
__global__ void transpose_kernel(const float* __restrict__ wq, const float* __restrict__ wk,
                                 const float* __restrict__ wv, const float* __restrict__ wo,
                                 const float* __restrict__ pwq,
                                 unsigned short* __restrict__ wqkvT,
                                 unsigned short* __restrict__ woT,
                                 unsigned short* __restrict__ pwqT) {
    __shared__ float t[32][33];
    int z = blockIdx.z;
    const float* W; unsigned short* Wt; int N;
    if (z == 0)      { W = wq;  Wt = wqkvT;              N = 768; }
    else if (z == 1) { W = wk;  Wt = wqkvT + 589824;     N = 768; }
    else if (z == 2) { W = wv;  Wt = wqkvT + 2 * 589824; N = 768; }
    else if (z == 3) { W = wo;  Wt = woT;                N = 768; }
    else             { W = pwq; Wt = pwqT;               N = 1024; }
    int k0 = blockIdx.x * 32, n0 = blockIdx.y * 32;
    if (n0 >= N) return;
    int tx = threadIdx.x, ty = threadIdx.y;
#pragma unroll
    for (int i = 0; i < 4; ++i)
        t[ty + 8 * i][tx] = W[(long)(k0 + ty + 8 * i) * N + n0 + tx];
    __syncthreads();
#pragma unroll
    for (int i = 0; i < 4; ++i)
        Wt[(long)(n0 + ty + 8 * i) * 768 + k0 + tx] = f2bf(t[tx][ty + 8 * i]);
}

// ---------------- elementwise f32 -> bf16 (keys) ----------------
__global__ void conv_kernel(const float* __restrict__ in, unsigned short* __restrict__ out, int n) {
    int i = blockIdx.x * blockDim.x + threadIdx.x;
    if (i < n) out[i] = f2bf(in[i]);
}

// ---------------- values table f32 -> bf16, vectorized stream ----------------
__global__ __launch_bounds__(256)
void convv_kernel(const float* __restrict__ in, unsigned short* __restrict__ out) {
    long i = ((long)blockIdx.x * 256 + threadIdx.x) * 8;
    f32x4 a = *(const f32x4*)(in + i);
    f32x4 b = *(const f32x4*)(in + i + 4);
    bf16x8 r;
#pragma unroll
    for (int j = 0; j < 4; ++j) { r[j] = (short)f2bf(a[j]); r[4 + j] = (short)f2bf(b[j]); }
    *(bf16x8*)(out + i) = r;
}

// ---------------- LayerNorm: x f32 [rows][768] -> bf16 ----------------
__global__ __launch_bounds__(256)
void ln_kernel(const float* __restrict__ x, const float* __restrict__ g,
               const float* __restrict__ b, unsigned short* __restrict__ out) {
    int row = blockIdx.x, tid = threadIdx.x;
    const float* xr = x + (long)row * D_;
    float v0 = xr[tid], v1 = xr[tid + 256], v2 = xr[tid + 512];
    float s = v0 + v1 + v2, ss = v0 * v0 + v1 * v1 + v2 * v2;
#pragma unroll
    for (int o = 1; o < 64; o <<= 1) { s += __shfl_xor(s, o); ss += __shfl_xor(ss, o); }
    __shared__ float ps[4], pss[4];
    int wid = tid >> 6, lane = tid & 63;
    if (lane == 0) { ps[wid] = s; pss[wid] = ss; }
    __syncthreads();
    s = ps[0] + ps[1] + ps[2] + ps[3];
    ss = pss[0] + pss[1] + pss[2] + pss[3];
    float mean = s * (1.f / D_);
    float var = ss * (1.f / D_) - mean * mean;
    float rs = rsqrtf(var + 1e-5f);
    unsigned short* orow = out + (long)row * D_;
    orow[tid]       = f2bf((v0 - mean) * rs * g[tid]       + b[tid]);
    orow[tid + 256] = f2bf((v1 - mean) * rs * g[tid + 256] + b[tid + 256]);
    orow[tid + 512] = f2bf((v2 - mean) * rs * g[tid + 512] + b[tid + 512]);
}

// ---------------- 128x128 MFMA GEMM (m97 structure): global_load_lds staging ----------------
// 4 waves, each owns a 64x64 quadrant (wr,wc); BK=32; linear LDS [128][32] shorts.
// qkv!=0: bias segment select for merged QKV output (cols 0/768/1536).
__global__ __launch_bounds__(256)
void gemm128_kernel(const unsigned short* __restrict__ A, int lda,
                    const unsigned short* __restrict__ Bt, int ldb,
                    const float* __restrict__ bias,
                    const float* __restrict__ bias2,
                    const float* __restrict__ bias3,
                    const float* __restrict__ res,
                    float* __restrict__ outF,
                    unsigned short* __restrict__ outB,
                    int ldc, int K, int qkv) {
    __shared__ unsigned short As[128 * 32];
    __shared__ unsigned short Bs[128 * 32];
    const int tid = threadIdx.x, w = tid >> 6, lane = tid & 63;
    const int ls = lane & 15, g = lane >> 4;
    const int wr = w >> 1, wc = w & 1;
    const int m0 = blockIdx.x * 128, n0 = blockIdx.y * 128;

    // wave w stages rows 32w..32w+31 of each tile; lane l -> row +(l>>2), k-slot (l&3)
    const unsigned short* gA = A + (long)(m0 + 32 * w + (lane >> 2)) * lda + (lane & 3) * 8;
    const unsigned short* gB = Bt + (long)(n0 + 32 * w + (lane >> 2)) * ldb + (lane & 3) * 8;
    unsigned short* lA = As + w * 1024;     // 2KB per wave region
    unsigned short* lB = Bs + w * 1024;
    const long a16 = 16 * (long)lda, b16 = 16 * (long)ldb;

    f32x4 acc[4][4];
#pragma unroll
    for (int c = 0; c < 4; ++c)
#pragma unroll
        for (int d = 0; d < 4; ++d) acc[c][d] = (f32x4){0.f, 0.f, 0.f, 0.f};

    for (int kt = 0; kt < K; kt += 32) {
        __syncthreads();                     // previous tile fully consumed
        gload16(gA + kt, lA);
        gload16(gA + kt + a16, lA + 512);
        gload16(gB + kt, lB);
        gload16(gB + kt + b16, lB + 512);
        __syncthreads();                     // compiler drains vmcnt before barrier

        bf16x8 af[4], bf[4];
#pragma unroll
        for (int c = 0; c < 4; ++c)
            af[c] = *(const bf16x8*)&As[(wr * 64 + c * 16 + ls) * 32 + g * 8];
#pragma unroll
        for (int d = 0; d < 4; ++d)
            bf[d] = *(const bf16x8*)&Bs[(wc * 64 + d * 16 + ls) * 32 + g * 8];
#pragma unroll
        for (int c = 0; c < 4; ++c)
#pragma unroll
            for (int d = 0; d < 4; ++d)
                acc[c][d] = __builtin_amdgcn_mfma_f32_16x16x32_bf16(af[c], bf[d], acc[c][d], 0, 0, 0);
    }

#pragma unroll
    for (int c = 0; c < 4; ++c)
#pragma unroll
        for (int d = 0; d < 4; ++d)
#pragma unroll
            for (int r = 0; r < 4; ++r) {
                int row = m0 + wr * 64 + c * 16 + g * 4 + r;
                int col = n0 + wc * 64 + d * 16 + ls;
                float v = acc[c][d][r];
                if (bias) {
                    const float* bp = bias; int cc = col;
                    if (qkv) {
                        int sel = col >= 1536 ? 2 : (col >= 768 ? 1 : 0);
                        bp = sel == 0 ? bias : (sel == 1 ? bias2 : bias3);
                        cc = col - sel * 768;
                    }
                    v += bp[cc];
                }
                long off = (long)row * ldc + col;
                if (res)  v += res[off];
                if (outF) outF[off] = v;
                if (outB) outB[off] = f2bf(v);
            }
}

// ---------------- 64x64 MFMA GEMM (dots only: K=128, zmode batching) ----------------
__global__ __launch_bounds__(256)
void gemm_kernel(const unsigned short* __restrict__ A, int lda,
                 const unsigned short* __restrict__ Bt, int ldb,
                 float* __restrict__ outF, int ldc, int K) {
    int z = blockIdx.z, ph = z >> 1, half = z & 1;
    A    += half * 512 + ph * 128;
    Bt   += ph * 65536 + half * 128;
    outF += ph * 512 + half * 256;
    const int tid = threadIdx.x;
    const int w = tid >> 6, lane = tid & 63;
    const int ls = lane & 15, g = lane >> 4;
    const int m0 = blockIdx.x * 64, n0 = blockIdx.y * 64;

    __shared__ unsigned short As[64][40];
    __shared__ unsigned short Bs[64][40];

    f32x4 acc[4];
#pragma unroll
    for (int c = 0; c < 4; ++c) acc[c] = (f32x4){0.f, 0.f, 0.f, 0.f};

    const int lrow = tid >> 2, lseg = tid & 3;
    const unsigned short* gA = A + (long)(m0 + lrow) * lda + lseg * 8;
    const unsigned short* gB = Bt + (long)(n0 + lrow) * ldb + lseg * 8;

    for (int kt = 0; kt < K; kt += 32) {
        __syncthreads();
        *(int4*)&As[lrow][lseg * 8] = *(const int4*)(gA + kt);
        *(int4*)&Bs[lrow][lseg * 8] = *(const int4*)(gB + kt);
        __syncthreads();
        bf16x8 bfr = *(const bf16x8*)&Bs[w * 16 + ls][g * 8];
#pragma unroll
        for (int c = 0; c < 4; ++c) {
            bf16x8 afr = *(const bf16x8*)&As[c * 16 + ls][g * 8];
            acc[c] = __builtin_amdgcn_mfma_f32_16x16x32_bf16(afr, bfr, acc[c], 0, 0, 0);
        }
    }
#pragma unroll
    for (int c = 0; c < 4; ++c)
#pragma unroll
        for (int r = 0; r < 4; ++r)
            outF[(long)(m0 + c * 16 + g * 4 + r) * ldc + n0 + w * 16 + ls] = acc[c][r];
}

// ---------------- MFMA flash attention (bf16 in/out, f32 online softmax) ----------------
__global__ __launch_bounds__(256)
void attn_mfma_kernel(const unsigned short* __restrict__ qkv,
                      unsigned short* __restrict__ outg) {
    int bh = blockIdx.x, bb = bh / H_, hh = bh % H_;
    int q0 = blockIdx.y * 64;
    int tid = threadIdx.x, wv = tid >> 6, lane = tid & 63;
    int ls = lane & 15, g = lane >> 4;

    __shared__ unsigned short Klds[128 * 64];
    __shared__ unsigned short Vlds[64 * 128];
    __shared__ unsigned short Plds[4][16 * 128];

    const unsigned short* qrow = qkv + (long)(bb * T_ + q0 + wv * 16 + ls) * QKVLD + hh * 64 + g * 8;
    bf16x8 qf0 = *(const bf16x8*)qrow;
    bf16x8 qf1 = *(const bf16x8*)(qrow + 32);

    f32x4 o_acc[4];
#pragma unroll
    for (int nf = 0; nf < 4; ++nf) o_acc[nf] = (f32x4){0.f, 0.f, 0.f, 0.f};
    float mrun[4] = {-1e30f, -1e30f, -1e30f, -1e30f};
    float lrun[4] = {0.f, 0.f, 0.f, 0.f};

    char* pbase = (char*)&Plds[wv][0];

    for (int kt = 0; kt < T_ / 128; ++kt) {
        int kvb = kt * 128;
        __syncthreads();
#pragma unroll
        for (int i = 0; i < 4; ++i) {
            int c = tid + i * 256;
            int kv = c >> 3, dc = c & 7;
            bf16x8 kd = *(const bf16x8*)(qkv + (long)(bb * T_ + kvb + kv) * QKVLD + 768 + hh * 64 + dc * 8);
            *(bf16x8*)((char*)Klds + ((kv * 128 + dc * 16) ^ ((kv & 7) << 4))) = kd;
        }
        {
            int d0 = (tid & 7) * 8, kvq = tid >> 3;
            const unsigned short* vb = qkv + (long)(bb * T_ + kvb + kvq * 4) * QKVLD + 1536 + hh * 64 + d0;
            bf16x8 r0 = *(const bf16x8*)(vb);
            bf16x8 r1 = *(const bf16x8*)(vb + QKVLD);
            bf16x8 r2 = *(const bf16x8*)(vb + 2 * QKVLD);
            bf16x8 r3 = *(const bf16x8*)(vb + 3 * QKVLD);
#pragma unroll
            for (int j = 0; j < 8; ++j) {
                unsigned lo = (unsigned)(unsigned short)r0[j] | ((unsigned)(unsigned short)r1[j] << 16);
                unsigned hi = (unsigned)(unsigned short)r2[j] | ((unsigned)(unsigned short)r3[j] << 16);
                int d = d0 + j;
                *(uint2*)((char*)Vlds + ((d * 256 + kvq * 8) ^ ((d & 7) << 4))) = make_uint2(lo, hi);
            }
        }
        __syncthreads();

        f32x4 sa[8];
#pragma unroll
        for (int f = 0; f < 8; ++f) sa[f] = (f32x4){0.f, 0.f, 0.f, 0.f};
#pragma unroll
        for (int f = 0; f < 8; ++f) {
            int kv = f * 16 + ls;
            bf16x8 b0 = *(const bf16x8*)((char*)Klds + ((kv * 128 + g * 16) ^ ((kv & 7) << 4)));
            bf16x8 b1 = *(const bf16x8*)((char*)Klds + ((kv * 128 + 64 + g * 16) ^ ((kv & 7) << 4)));
            sa[f] = __builtin_amdgcn_mfma_f32_16x16x32_bf16(qf0, b0, sa[f], 0, 0, 0);
            sa[f] = __builtin_amdgcn_mfma_f32_16x16x32_bf16(qf1, b1, sa[f], 0, 0, 0);
        }

        float pw[8][4];
#pragma unroll
        for (int f = 0; f < 8; ++f)
#pragma unroll
            for (int r = 0; r < 4; ++r) pw[f][r] = sa[f][r] * 0.125f;
        float nm[4], fac[4];
#pragma unroll
        for (int r = 0; r < 4; ++r) {
            float m = pw[0][r];
#pragma unroll
            for (int f = 1; f < 8; ++f) m = fmaxf(m, pw[f][r]);
            m = fmaxf(m, __shfl_xor(m, 1));
            m = fmaxf(m, __shfl_xor(m, 2));
            m = fmaxf(m, __shfl_xor(m, 4));
            m = fmaxf(m, __shfl_xor(m, 8));
            nm[r] = fmaxf(mrun[r], m);
            fac[r] = __expf(mrun[r] - nm[r]);
            mrun[r] = nm[r];
        }
#pragma unroll
        for (int r = 0; r < 4; ++r) {
            float s = 0.f;
#pragma unroll
            for (int f = 0; f < 8; ++f) { float e = __expf(pw[f][r] - nm[r]); pw[f][r] = e; s += e; }
            s += __shfl_xor(s, 1); s += __shfl_xor(s, 2);
            s += __shfl_xor(s, 4); s += __shfl_xor(s, 8);
            lrun[r] = lrun[r] * fac[r] + s;
#pragma unroll
            for (int nf = 0; nf < 4; ++nf) o_acc[nf][r] *= fac[r];
        }

#pragma unroll
        for (int f = 0; f < 8; ++f)
#pragma unroll
            for (int r = 0; r < 4; ++r) {
                int qr = g * 4 + r, col = ls + 16 * f;
                *(unsigned short*)(pbase + ((qr * 256 + col * 2) ^ ((qr & 7) << 4))) = f2bf(pw[f][r]);
            }

#pragma unroll
        for (int ks = 0; ks < 4; ++ks) {
            bf16x8 pa = *(const bf16x8*)(pbase + ((ls * 256 + ks * 64 + g * 16) ^ ((ls & 7) << 4)));
#pragma unroll
            for (int nf = 0; nf < 4; ++nf) {
                int d = nf * 16 + ls;
                bf16x8 bv = *(const bf16x8*)((char*)Vlds + ((d * 256 + ks * 64 + g * 16) ^ ((d & 7) << 4)));
                o_acc[nf] = __builtin_amdgcn_mfma_f32_16x16x32_bf16(pa, bv, o_acc[nf], 0, 0, 0);
            }
        }
    }

    float inv[4];
#pragma unroll
    for (int r = 0; r < 4; ++r) inv[r] = 1.f / lrun[r];
#pragma unroll
    for (int nf = 0; nf < 4; ++nf)
#pragma unroll
        for (int r = 0; r < 4; ++r) {
            long row = bb * T_ + q0 + wv * 16 + g * 4 + r;
            outg[row * D_ + hh * 64 + nf * 16 + ls] = f2bf(o_acc[nf][r] * inv[r]);
        }
}

// ---------------- BatchNorm over tokens (deterministic two-stage) ----------------
__global__ __launch_bounds__(256)
void bn_part(const float* __restrict__ qf, float* __restrict__ pS, float* __restrict__ pSS) {
    int c = blockIdx.y * 256 + threadIdx.x;
    int r0 = blockIdx.x * 256;
    float s = 0.f, ss = 0.f;
    for (int r = 0; r < 256; ++r) {
        float v = qf[(long)(r0 + r) * DQ_ + c];
        s += v; ss += v * v;
    }
    pS[blockIdx.x * DQ_ + c] = s;
    pSS[blockIdx.x * DQ_ + c] = ss;
}

__global__ __launch_bounds__(256)
void bn_fin(const float* __restrict__ pS, const float* __restrict__ pSS,
            float* __restrict__ mu, float* __restrict__ rs) {
    int c = blockIdx.x * 256 + threadIdx.x;
    float s = 0.f, ss = 0.f;
#pragma unroll
    for (int i = 0; i < 8; ++i) { s += pS[i * DQ_ + c]; ss += pSS[i * DQ_ + c]; }
    float m = s * (1.f / NT);
    float var = ss * (1.f / NT) - m * m;
    mu[c] = m;
    rs[c] = rsqrtf(var + 1e-5f);
}

__global__ __launch_bounds__(256)
void qn_kernel(const float* __restrict__ qf, const float* __restrict__ mu,
               const float* __restrict__ rs, const float* __restrict__ g,
               const float* __restrict__ b, unsigned short* __restrict__ qn) {
    int i = blockIdx.x * 256 + threadIdx.x;
    int c = i & (DQ_ - 1);
    qn[i] = f2bf((qf[i] - mu[c]) * rs[c] * g[c] + b[c]);
}

// ---------------- fused top-k ----------------
__global__ __launch_bounds__(256)
void topk_kernel(const float* __restrict__ dots, float* __restrict__ fs, int* __restrict__ vi) {
    static const unsigned short tab[128] = {
        0,1,2,3,4,5,6,7,8,9,10,11,12,13,14,15,16,17,18,19,20,21,22,23,24,25,26,27,28,29,30,31,
        32,33,34,35,36,37,38,39,40,41,42,43,44,45,46,47,
        64,65,66,67,68,69,70,71,72,73,
        96,97,98,99,100,101,102,103,
        128,129,130,131,132,133,
        160,161,162,163,164,
        192,193,194,195,
        224,225,226,227,
        256,257,258,
        288,289,290,
        320,321, 352,353, 384,385, 416,417, 448,449, 480,481,
        512,544,576,608,640,672,704,736,768,800,832,864,896,928,960,992,
        0xFFFF,0xFFFF,0xFFFF,0xFFFF,0xFFFF,0xFFFF,0xFFFF,0xFFFF,0xFFFF
    };
    __shared__ float sv[4][64];
    __shared__ int   sidx[4][64];
    int tid = threadIdx.x, wv = tid >> 6, lane = tid & 63;
    long task = (long)blockIdx.x * 4 + wv;
    const float* dbase = dots + (task >> 2) * 2048 + (task & 3) * 512;

#pragma unroll 1
    for (int half = 0; half < 2; ++half) {
        const float* d = dbase + half * 256;
        float v0 = d[lane], v1 = d[lane + 64], v2 = d[lane + 128], v3 = d[lane + 192];
#pragma unroll 1
        for (int t = 0; t < 32; ++t) {
            float bm = v0; int ba = 0;
            if (v1 > bm) { bm = v1; ba = 1; }
            if (v2 > bm) { bm = v2; ba = 2; }
            if (v3 > bm) { bm = v3; ba = 3; }
            float wm = bm;
#pragma unroll
            for (int o = 32; o >= 1; o >>= 1) wm = fmaxf(wm, __shfl_xor(wm, o));
            unsigned long long msk = __ballot(bm == wm);
            int owner = (int)__builtin_ctzll(msk);
            if (lane == owner) {
                sv[wv][half * 32 + t] = wm;
                sidx[wv][half * 32 + t] = ba * 64 + lane;
                if (ba == 0) v0 = -1e30f;
                else if (ba == 1) v1 = -1e30f;
                else if (ba == 2) v2 = -1e30f;
                else v3 = -1e30f;
            }
        }
    }
    __syncthreads();

    unsigned short t0 = tab[lane], t1 = tab[lane + 64];
    float v0 = -1e30f, v1 = -1e30f;
    int id0 = 0, id1 = 0;
    {
        int i = t0 >> 5, j = t0 & 31;
        v0 = sv[wv][i] + sv[wv][32 + j];
        id0 = sidx[wv][i] * NK_ + sidx[wv][32 + j];
    }
    if (t1 != 0xFFFF) {
        int i = t1 >> 5, j = t1 & 31;
        v1 = sv[wv][i] + sv[wv][32 + j];
        id1 = sidx[wv][i] * NK_ + sidx[wv][32 + j];
    }

    float* fo = fs + task * 32;
    int*   vo = vi + task * 32;
#pragma unroll 1
    for (int t = 0; t < 32; ++t) {
        float bm = v0; int sel = 0;
        if (v1 > bm) { bm = v1; sel = 1; }
        float wm = bm;
#pragma unroll
        for (int o = 32; o >= 1; o >>= 1) wm = fmaxf(wm, __shfl_xor(wm, o));
        unsigned long long msk = __ballot(bm == wm);
        int owner = (int)__builtin_ctzll(msk);
        if (lane == owner) {
            fo[t] = wm;
            vo[t] = sel ? id1 : id0;
            if (sel) v1 = -1e30f; else v0 = -1e30f;
        }
    }
}

// ---------------- softmax + gather(bf16 table) + residual ----------------
// 384 threads = 4 row-slots x 96 chunks of 8 bf16 (16B/lane).
__global__ __launch_bounds__(384)
void pkm_out_bf16(const float* __restrict__ fs, const int* __restrict__ vi,
                  const unsigned short* __restrict__ valsb, const float* __restrict__ x1,
                  float* __restrict__ outp) {
    int n = blockIdx.x, tid = threadIdx.x;
    __shared__ float w[128];
    __shared__ int   rows[128];
    __shared__ float red[3 * 768];
    if (tid < 128) {
        float e = fs[(long)n * 128 + tid];
        rows[tid] = vi[(long)n * 128 + tid];
        float m = e;
#pragma unroll
        for (int o = 16; o >= 1; o >>= 1) m = fmaxf(m, __shfl_xor(m, o));
        float ex = __expf(e - m);
        float s = ex;
#pragma unroll
        for (int o = 16; o >= 1; o >>= 1) s += __shfl_xor(s, o);
        w[tid] = ex / s;
    }
    __syncthreads();
    int slot = tid / 96, chunk = tid % 96;
    float a0=0.f,a1=0.f,a2=0.f,a3=0.f,a4=0.f,a5=0.f,a6=0.f,a7=0.f;
#pragma unroll 4
    for (int e = 0; e < 32; ++e) {
        int er = e * 4 + slot;
        float wgt = w[er];
        long ro = (long)rows[er] * D_;
        bf16x8 v = *(const bf16x8*)(valsb + ro + chunk * 8);
        a0 += wgt * bf2f((unsigned short)v[0]); a1 += wgt * bf2f((unsigned short)v[1]);
        a2 += wgt * bf2f((unsigned short)v[2]); a3 += wgt * bf2f((unsigned short)v[3]);
        a4 += wgt * bf2f((unsigned short)v[4]); a5 += wgt * bf2f((unsigned short)v[5]);
        a6 += wgt * bf2f((unsigned short)v[6]); a7 += wgt * bf2f((unsigned short)v[7]);
    }
    if (slot > 0) {
        float* rp = &red[(slot - 1) * 768 + chunk * 8];
        rp[0]=a0; rp[1]=a1; rp[2]=a2; rp[3]=a3; rp[4]=a4; rp[5]=a5; rp[6]=a6; rp[7]=a7;
    }
    __syncthreads();
    if (slot == 0) {
        long o = (long)n * D_ + chunk * 8;
        const float* r0 = &red[chunk * 8];
        const float* r1 = &red[768 + chunk * 8];
        const float* r2 = &red[1536 + chunk * 8];
        f32x4 xa = *(const f32x4*)(x1 + o);
        f32x4 xb = *(const f32x4*)(x1 + o + 4);
        f32x4 o1 = { a0 + r0[0] + r1[0] + r2[0] + xa[0], a1 + r0[1] + r1[1] + r2[1] + xa[1],
                     a2 + r0[2] + r1[2] + r2[2] + xa[2], a3 + r0[3] + r1[3] + r2[3] + xa[3] };
        f32x4 o2 = { a4 + r0[4] + r1[4] + r2[4] + xb[0], a5 + r0[5] + r1[5] + r2[5] + xb[1],
                     a6 + r0[6] + r1[6] + r2[6] + xb[2], a7 + r0[7] + r1[7] + r2[7] + xb[3] };
        *(f32x4*)(outp + o) = o1;
        *(f32x4*)(outp + o + 4) = o2;
    }
}

// ---------------- fallback: f32-table gather (round-4 structure) ----------------
__global__ __launch_bounds__(384)
void pkm_out_f32(const float* __restrict__ fs, const int* __restrict__ vi,
                 const float* __restrict__ values, const float* __restrict__ x1,
                 float* __restrict__ outp) {
    int n = blockIdx.x, tid = threadIdx.x;
    __shared__ float w[128];
    __shared__ int   rows[128];
    __shared__ float red[768];
    if (tid < 128) {
        float e = fs[(long)n * 128 + tid];
        rows[tid] = vi[(long)n * 128 + tid];
        float m = e;
#pragma unroll
        for (int o = 16; o >= 1; o >>= 1) m = fmaxf(m, __shfl_xor(m, o));
        float ex = __expf(e - m);
        float s = ex;
#pragma unroll
        for (int o = 16; o >= 1; o >>= 1) s += __shfl_xor(s, o);
        w[tid] = ex / s;
    }
    __syncthreads();
    int slot = tid / 192, chunk = tid % 192;
    float a0 = 0.f, a1 = 0.f, a2 = 0.f, a3 = 0.f;
#pragma unroll 4
    for (int e = 0; e < 64; ++e) {
        int er = e * 2 + slot;
        float wgt = w[er];
        long ro = (long)rows[er] * D_;
        f32x4 v = *(const f32x4*)(values + ro + chunk * 4);
        a0 += wgt * v[0]; a1 += wgt * v[1]; a2 += wgt * v[2]; a3 += wgt * v[3];
    }
    if (slot == 1) {
        f32x4 t = {a0, a1, a2, a3};
        *(f32x4*)&red[chunk * 4] = t;
    }
    __syncthreads();
    if (slot == 0) {
        f32x4 o = *(const f32x4*)&red[chunk * 4];
        f32x4 xr = *(const f32x4*)(x1 + (long)n * D_ + chunk * 4);
        o[0] += a0 + xr[0]; o[1] += a1 + xr[1]; o[2] += a2 + xr[2]; o[3] += a3 + xr[3];
        *(f32x4*)(outp + (long)n * D_ + chunk * 4) = o;
    }
}

extern "C" void kernel_launch(void* const* d_in, const int* in_sizes, int n_in,
                              void* d_out, int out_size, void* d_ws, size_t ws_size,
                              hipStream_t stream) {
    const float* x    = (const float*)d_in[0];
    const float* wq   = (const float*)d_in[1];
    const float* bq   = (const float*)d_in[2];
    const float* wk   = (const float*)d_in[3];
    const float* bk   = (const float*)d_in[4];
    const float* wv   = (const float*)d_in[5];
    const float* bv   = (const float*)d_in[6];
    const float* wo   = (const float*)d_in[7];
    const float* bo   = (const float*)d_in[8];
    const float* ln1g = (const float*)d_in[9];
    const float* ln1b = (const float*)d_in[10];
    const float* ln2g = (const float*)d_in[11];
    const float* ln2b = (const float*)d_in[12];
    const float* pwq  = (const float*)d_in[13];
    const float* bng  = (const float*)d_in[14];
    const float* bnb  = (const float*)d_in[15];
    const float* keys = (const float*)d_in[16];
    const float* vals = (const float*)d_in[17];
    float* out = (float*)d_out;

    char* p = (char*)d_ws;
    auto alloc = [&](size_t bytes) -> char* {
        char* r = p; p += (bytes + 255) & ~(size_t)255; return r;
    };
    unsigned short* wqkvT = (unsigned short*)alloc((size_t)3 * D_ * D_ * 2);
    unsigned short* woT   = (unsigned short*)alloc((size_t)D_ * D_ * 2);
    unsigned short* pwqT  = (unsigned short*)alloc((size_t)D_ * DQ_ * 2);
    unsigned short* keyB  = (unsigned short*)alloc((size_t)PH_ * NK_ * 2 * DHK_ * 2);
    unsigned short* h1    = (unsigned short*)alloc((size_t)NT * D_ * 2);
    unsigned short* qkvB  = (unsigned short*)alloc((size_t)NT * QKVLD * 2);
    unsigned short* aout  = (unsigned short*)alloc((size_t)NT * D_ * 2);
    float* x1             = (float*)alloc((size_t)NT * D_ * 4);
    unsigned short* h2    = (unsigned short*)alloc((size_t)NT * D_ * 2);
    float* qf             = (float*)alloc((size_t)NT * DQ_ * 4);
    float* pS             = (float*)alloc((size_t)8 * DQ_ * 4);
    float* pSS            = (float*)alloc((size_t)8 * DQ_ * 4);
    float* mu             = (float*)alloc((size_t)DQ_ * 4);
    float* rs             = (float*)alloc((size_t)DQ_ * 4);
    unsigned short* qnB   = (unsigned short*)alloc((size_t)NT * DQ_ * 2);
    float* dots           = (float*)alloc((size_t)NT * 2048 * 4);
    float* fsb            = (float*)alloc((size_t)NT * PH_ * 32 * 4);
    int*   vib            = (int*)alloc((size_t)NT * PH_ * 32 * 4);

    // bf16 values table if workspace allows (needs ~100.7 MB more)
    size_t used = (size_t)(p - (char*)d_ws);
    size_t vbytes = (size_t)NK_ * NK_ * D_ * 2;
    bool useBf = (used + vbytes + 256) <= ws_size;
    unsigned short* valsb = nullptr;
    if (useBf) valsb = (unsigned short*)alloc(vbytes);

    // weight prep
    transpose_kernel<<<dim3(24, 32, 5), dim3(32, 8), 0, stream>>>(wq, wk, wv, wo, pwq, wqkvT, woT, pwqT);
    conv_kernel<<<(PH_ * NK_ * 2 * DHK_) / 256, 256, 0, stream>>>(keys, keyB, PH_ * NK_ * 2 * DHK_);
    if (useBf)
        convv_kernel<<<(NK_ * NK_ * D_) / (256 * 8), 256, 0, stream>>>(vals, valsb);

    // LN1
    ln_kernel<<<NT, 256, 0, stream>>>(x, ln1g, ln1b, h1);
    // merged QKV GEMM -> qkvB [2048][2304] bf16
    gemm128_kernel<<<dim3(16, 18), 256, 0, stream>>>(h1, D_, wqkvT, D_, bq, bk, bv, nullptr, nullptr, qkvB, QKVLD, D_, 1);
    // attention (MFMA flash)
    attn_mfma_kernel<<<dim3(B_ * H_, T_ / 64), 256, 0, stream>>>(qkvB, aout);
    // output projection + residual
    gemm128_kernel<<<dim3(16, 6), 256, 0, stream>>>(aout, D_, woT, D_, bo, nullptr, nullptr, x, x1, nullptr, D_, D_, 0);
    // LN2 + PKM query
    ln_kernel<<<NT, 256, 0, stream>>>(x1, ln2g, ln2b, h2);
    gemm128_kernel<<<dim3(16, 8), 256, 0, stream>>>(h2, D_, pwqT, D_, nullptr, nullptr, nullptr, nullptr, qf, nullptr, DQ_, D_, 0);
    // BatchNorm
    bn_part<<<dim3(8, 4), 256, 0, stream>>>(qf, pS, pSS);
    bn_fin<<<4, 256, 0, stream>>>(pS, pSS, mu, rs);
    qn_kernel<<<(NT * DQ_) / 256, 256, 0, stream>>>(qf, mu, rs, bng, bnb, qnB);
    // dots: 8 batched GEMMs via blockIdx.z
    gemm_kernel<<<dim3(32, 4, 8), 256, 0, stream>>>(qnB, DQ_, keyB, 256, dots, 2048, DHK_);
    // fused top-k
    topk_kernel<<<(NT * PH_) / 4, 256, 0, stream>>>(dots, fsb, vib);
    // softmax + gather + residual
    if (useBf)
        pkm_out_bf16<<<NT, 384, 0, stream>>>(fsb, vib, valsb, x1, out);
    else
        pkm_out_f32<<<NT, 384, 0, stream>>>(fsb, vib, vals, x1, out);
}

// Round 7
// 322.184 us; speedup vs baseline: 1.1182x; 1.1182x over previous
//
#include <hip/hip_runtime.h>
#include <hip/hip_bf16.h>

#define B_  2
#define T_  1024
#define D_  768
#define H_  12
#define NT  2048        // B*T
#define DQ_ 1024
#define PH_ 4
#define NK_ 256
#define TK_ 32
#define DHK_ 128
#define QKVLD 2304      // merged QKV row stride

typedef __attribute__((ext_vector_type(8))) short bf16x8;
typedef __attribute__((ext_vector_type(4))) float f32x4;

static __device__ __forceinline__ unsigned short f2bf(float f) {
    union { float f; unsigned u; } c; c.f = f;
    unsigned r = (c.u + 0x7fffu + ((c.u >> 16) & 1u)) >> 16;
    return (unsigned short)r;
}

static __device__ __forceinline__ float bf2f(unsigned short s) {
    union { unsigned u; float f; } c; c.u = ((unsigned)s) << 16;
    return c.f;
}

// ---------------- batched transpose+convert: 5 weight matrices in one launch ----------------
__global__ void transpose_kernel(const float* __restrict__ wq, const float* __restrict__ wk,
                                 const float* __restrict__ wv, const float* __restrict__ wo,
                                 const float* __restrict__ pwq,
                                 unsigned short* __restrict__ wqkvT,
                                 unsigned short* __restrict__ woT,
                                 unsigned short* __restrict__ pwqT) {
    __shared__ float t[32][33];
    int z = blockIdx.z;
    const float* W; unsigned short* Wt; int N;
    if (z == 0)      { W = wq;  Wt = wqkvT;              N = 768; }
    else if (z == 1) { W = wk;  Wt = wqkvT + 589824;     N = 768; }
    else if (z == 2) { W = wv;  Wt = wqkvT + 2 * 589824; N = 768; }
    else if (z == 3) { W = wo;  Wt = woT;                N = 768; }
    else             { W = pwq; Wt = pwqT;               N = 1024; }
    int k0 = blockIdx.x * 32, n0 = blockIdx.y * 32;
    if (n0 >= N) return;
    int tx = threadIdx.x, ty = threadIdx.y;
#pragma unroll
    for (int i = 0; i < 4; ++i)
        t[ty + 8 * i][tx] = W[(long)(k0 + ty + 8 * i) * N + n0 + tx];
    __syncthreads();
#pragma unroll
    for (int i = 0; i < 4; ++i)
        Wt[(long)(n0 + ty + 8 * i) * 768 + k0 + tx] = f2bf(t[tx][ty + 8 * i]);
}

// ---------------- elementwise f32 -> bf16 (keys) ----------------
__global__ void conv_kernel(const float* __restrict__ in, unsigned short* __restrict__ out, int n) {
    int i = blockIdx.x * blockDim.x + threadIdx.x;
    if (i < n) out[i] = f2bf(in[i]);
}

// ---------------- values table f32 -> bf16, vectorized stream ----------------
__global__ __launch_bounds__(256)
void convv_kernel(const float* __restrict__ in, unsigned short* __restrict__ out) {
    long i = ((long)blockIdx.x * 256 + threadIdx.x) * 8;
    f32x4 a = *(const f32x4*)(in + i);
    f32x4 b = *(const f32x4*)(in + i + 4);
    bf16x8 r;
#pragma unroll
    for (int j = 0; j < 4; ++j) { r[j] = (short)f2bf(a[j]); r[4 + j] = (short)f2bf(b[j]); }
    *(bf16x8*)(out + i) = r;
}

// ---------------- LayerNorm: x f32 [rows][768] -> bf16 ----------------
__global__ __launch_bounds__(256)
void ln_kernel(const float* __restrict__ x, const float* __restrict__ g,
               const float* __restrict__ b, unsigned short* __restrict__ out) {
    int row = blockIdx.x, tid = threadIdx.x;
    const float* xr = x + (long)row * D_;
    float v0 = xr[tid], v1 = xr[tid + 256], v2 = xr[tid + 512];
    float s = v0 + v1 + v2, ss = v0 * v0 + v1 * v1 + v2 * v2;
#pragma unroll
    for (int o = 1; o < 64; o <<= 1) { s += __shfl_xor(s, o); ss += __shfl_xor(ss, o); }
    __shared__ float ps[4], pss[4];
    int wid = tid >> 6, lane = tid & 63;
    if (lane == 0) { ps[wid] = s; pss[wid] = ss; }
    __syncthreads();
    s = ps[0] + ps[1] + ps[2] + ps[3];
    ss = pss[0] + pss[1] + pss[2] + pss[3];
    float mean = s * (1.f / D_);
    float var = ss * (1.f / D_) - mean * mean;
    float rs = rsqrtf(var + 1e-5f);
    unsigned short* orow = out + (long)row * D_;
    orow[tid]       = f2bf((v0 - mean) * rs * g[tid]       + b[tid]);
    orow[tid + 256] = f2bf((v1 - mean) * rs * g[tid + 256] + b[tid + 256]);
    orow[tid + 512] = f2bf((v2 - mean) * rs * g[tid + 512] + b[tid + 512]);
}

// ---------------- MFMA GEMM: C[M,N] = A[M,K](bf16,lda) @ Bt[N,K](bf16,ldb)^T ----------------
// 64x64 tile, 4 waves, BK=32.
// zmode 1: dots batching over blockIdx.z. zmode 2: merged QKV (bias segment select).
__global__ __launch_bounds__(256)
void gemm_kernel(const unsigned short* __restrict__ A, int lda,
                 const unsigned short* __restrict__ Bt, int ldb,
                 const float* __restrict__ bias,
                 const float* __restrict__ bias2,
                 const float* __restrict__ bias3,
                 const float* __restrict__ res,
                 float* __restrict__ outF,
                 unsigned short* __restrict__ outB,
                 int ldc, int K, int zmode) {
    if (zmode == 1) {
        int z = blockIdx.z, ph = z >> 1, half = z & 1;
        A    += half * 512 + ph * 128;
        Bt   += ph * 65536 + half * 128;
        outF += ph * 512 + half * 256;
    }
    const int tid = threadIdx.x;
    const int w = tid >> 6, lane = tid & 63;
    const int ls = lane & 15, g = lane >> 4;
    const int m0 = blockIdx.x * 64, n0 = blockIdx.y * 64;

    __shared__ unsigned short As[64][40];
    __shared__ unsigned short Bs[64][40];

    f32x4 acc[4];
#pragma unroll
    for (int c = 0; c < 4; ++c) acc[c] = (f32x4){0.f, 0.f, 0.f, 0.f};

    const int lrow = tid >> 2, lseg = tid & 3;
    const unsigned short* gA = A + (long)(m0 + lrow) * lda + lseg * 8;
    const unsigned short* gB = Bt + (long)(n0 + lrow) * ldb + lseg * 8;

    for (int kt = 0; kt < K; kt += 32) {
        __syncthreads();
        *(int4*)&As[lrow][lseg * 8] = *(const int4*)(gA + kt);
        *(int4*)&Bs[lrow][lseg * 8] = *(const int4*)(gB + kt);
        __syncthreads();
        bf16x8 bfr = *(const bf16x8*)&Bs[w * 16 + ls][g * 8];
#pragma unroll
        for (int c = 0; c < 4; ++c) {
            bf16x8 afr = *(const bf16x8*)&As[c * 16 + ls][g * 8];
            acc[c] = __builtin_amdgcn_mfma_f32_16x16x32_bf16(afr, bfr, acc[c], 0, 0, 0);
        }
    }
#pragma unroll
    for (int c = 0; c < 4; ++c) {
#pragma unroll
        for (int r = 0; r < 4; ++r) {
            int row = m0 + c * 16 + g * 4 + r;
            int col = n0 + w * 16 + ls;
            float v = acc[c][r];
            if (bias) {
                const float* bp = bias; int cc = col;
                if (zmode == 2) {
                    int sel = col >= 1536 ? 2 : (col >= 768 ? 1 : 0);
                    bp = sel == 0 ? bias : (sel == 1 ? bias2 : bias3);
                    cc = col - sel * 768;
                }
                v += bp[cc];
            }
            long off = (long)row * ldc + col;
            if (res)  v += res[off];
            if (outF) outF[off] = v;
            if (outB) outB[off] = f2bf(v);
        }
    }
}

// ---------------- MFMA flash attention (bf16 in/out, f32 online softmax) ----------------
__global__ __launch_bounds__(256)
void attn_mfma_kernel(const unsigned short* __restrict__ qkv,
                      unsigned short* __restrict__ outg) {
    int bh = blockIdx.x, bb = bh / H_, hh = bh % H_;
    int q0 = blockIdx.y * 64;
    int tid = threadIdx.x, wv = tid >> 6, lane = tid & 63;
    int ls = lane & 15, g = lane >> 4;

    __shared__ unsigned short Klds[128 * 64];
    __shared__ unsigned short Vlds[64 * 128];
    __shared__ unsigned short Plds[4][16 * 128];

    const unsigned short* qrow = qkv + (long)(bb * T_ + q0 + wv * 16 + ls) * QKVLD + hh * 64 + g * 8;
    bf16x8 qf0 = *(const bf16x8*)qrow;
    bf16x8 qf1 = *(const bf16x8*)(qrow + 32);

    f32x4 o_acc[4];
#pragma unroll
    for (int nf = 0; nf < 4; ++nf) o_acc[nf] = (f32x4){0.f, 0.f, 0.f, 0.f};
    float mrun[4] = {-1e30f, -1e30f, -1e30f, -1e30f};
    float lrun[4] = {0.f, 0.f, 0.f, 0.f};

    char* pbase = (char*)&Plds[wv][0];

    for (int kt = 0; kt < T_ / 128; ++kt) {
        int kvb = kt * 128;
        __syncthreads();
#pragma unroll
        for (int i = 0; i < 4; ++i) {
            int c = tid + i * 256;
            int kv = c >> 3, dc = c & 7;
            bf16x8 kd = *(const bf16x8*)(qkv + (long)(bb * T_ + kvb + kv) * QKVLD + 768 + hh * 64 + dc * 8);
            *(bf16x8*)((char*)Klds + ((kv * 128 + dc * 16) ^ ((kv & 7) << 4))) = kd;
        }
        {
            int d0 = (tid & 7) * 8, kvq = tid >> 3;
            const unsigned short* vb = qkv + (long)(bb * T_ + kvb + kvq * 4) * QKVLD + 1536 + hh * 64 + d0;
            bf16x8 r0 = *(const bf16x8*)(vb);
            bf16x8 r1 = *(const bf16x8*)(vb + QKVLD);
            bf16x8 r2 = *(const bf16x8*)(vb + 2 * QKVLD);
            bf16x8 r3 = *(const bf16x8*)(vb + 3 * QKVLD);
#pragma unroll
            for (int j = 0; j < 8; ++j) {
                unsigned lo = (unsigned)(unsigned short)r0[j] | ((unsigned)(unsigned short)r1[j] << 16);
                unsigned hi = (unsigned)(unsigned short)r2[j] | ((unsigned)(unsigned short)r3[j] << 16);
                int d = d0 + j;
                *(uint2*)((char*)Vlds + ((d * 256 + kvq * 8) ^ ((d & 7) << 4))) = make_uint2(lo, hi);
            }
        }
        __syncthreads();

        f32x4 sa[8];
#pragma unroll
        for (int f = 0; f < 8; ++f) sa[f] = (f32x4){0.f, 0.f, 0.f, 0.f};
#pragma unroll
        for (int f = 0; f < 8; ++f) {
            int kv = f * 16 + ls;
            bf16x8 b0 = *(const bf16x8*)((char*)Klds + ((kv * 128 + g * 16) ^ ((kv & 7) << 4)));
            bf16x8 b1 = *(const bf16x8*)((char*)Klds + ((kv * 128 + 64 + g * 16) ^ ((kv & 7) << 4)));
            sa[f] = __builtin_amdgcn_mfma_f32_16x16x32_bf16(qf0, b0, sa[f], 0, 0, 0);
            sa[f] = __builtin_amdgcn_mfma_f32_16x16x32_bf16(qf1, b1, sa[f], 0, 0, 0);
        }

        float pw[8][4];
#pragma unroll
        for (int f = 0; f < 8; ++f)
#pragma unroll
            for (int r = 0; r < 4; ++r) pw[f][r] = sa[f][r] * 0.125f;
        float nm[4], fac[4];
#pragma unroll
        for (int r = 0; r < 4; ++r) {
            float m = pw[0][r];
#pragma unroll
            for (int f = 1; f < 8; ++f) m = fmaxf(m, pw[f][r]);
            m = fmaxf(m, __shfl_xor(m, 1));
            m = fmaxf(m, __shfl_xor(m, 2));
            m = fmaxf(m, __shfl_xor(m, 4));
            m = fmaxf(m, __shfl_xor(m, 8));
            nm[r] = fmaxf(mrun[r], m);
            fac[r] = __expf(mrun[r] - nm[r]);
            mrun[r] = nm[r];
        }
#pragma unroll
        for (int r = 0; r < 4; ++r) {
            float s = 0.f;
#pragma unroll
            for (int f = 0; f < 8; ++f) { float e = __expf(pw[f][r] - nm[r]); pw[f][r] = e; s += e; }
            s += __shfl_xor(s, 1); s += __shfl_xor(s, 2);
            s += __shfl_xor(s, 4); s += __shfl_xor(s, 8);
            lrun[r] = lrun[r] * fac[r] + s;
#pragma unroll
            for (int nf = 0; nf < 4; ++nf) o_acc[nf][r] *= fac[r];
        }

#pragma unroll
        for (int f = 0; f < 8; ++f)
#pragma unroll
            for (int r = 0; r < 4; ++r) {
                int qr = g * 4 + r, col = ls + 16 * f;
                *(unsigned short*)(pbase + ((qr * 256 + col * 2) ^ ((qr & 7) << 4))) = f2bf(pw[f][r]);
            }

#pragma unroll
        for (int ks = 0; ks < 4; ++ks) {
            bf16x8 pa = *(const bf16x8*)(pbase + ((ls * 256 + ks * 64 + g * 16) ^ ((ls & 7) << 4)));
#pragma unroll
            for (int nf = 0; nf < 4; ++nf) {
                int d = nf * 16 + ls;
                bf16x8 bv = *(const bf16x8*)((char*)Vlds + ((d * 256 + ks * 64 + g * 16) ^ ((d & 7) << 4)));
                o_acc[nf] = __builtin_amdgcn_mfma_f32_16x16x32_bf16(pa, bv, o_acc[nf], 0, 0, 0);
            }
        }
    }

    float inv[4];
#pragma unroll
    for (int r = 0; r < 4; ++r) inv[r] = 1.f / lrun[r];
#pragma unroll
    for (int nf = 0; nf < 4; ++nf)
#pragma unroll
        for (int r = 0; r < 4; ++r) {
            long row = bb * T_ + q0 + wv * 16 + g * 4 + r;
            outg[row * D_ + hh * 64 + nf * 16 + ls] = f2bf(o_acc[nf][r] * inv[r]);
        }
}

// ---------------- BatchNorm over tokens (deterministic two-stage) ----------------
__global__ __launch_bounds__(256)
void bn_part(const float* __restrict__ qf, float* __restrict__ pS, float* __restrict__ pSS) {
    int c = blockIdx.y * 256 + threadIdx.x;
    int r0 = blockIdx.x * 256;
    float s = 0.f, ss = 0.f;
    for (int r = 0; r < 256; ++r) {
        float v = qf[(long)(r0 + r) * DQ_ + c];
        s += v; ss += v * v;
    }
    pS[blockIdx.x * DQ_ + c] = s;
    pSS[blockIdx.x * DQ_ + c] = ss;
}

__global__ __launch_bounds__(256)
void bn_fin(const float* __restrict__ pS, const float* __restrict__ pSS,
            float* __restrict__ mu, float* __restrict__ rs) {
    int c = blockIdx.x * 256 + threadIdx.x;
    float s = 0.f, ss = 0.f;
#pragma unroll
    for (int i = 0; i < 8; ++i) { s += pS[i * DQ_ + c]; ss += pSS[i * DQ_ + c]; }
    float m = s * (1.f / NT);
    float var = ss * (1.f / NT) - m * m;
    mu[c] = m;
    rs[c] = rsqrtf(var + 1e-5f);
}

__global__ __launch_bounds__(256)
void qn_kernel(const float* __restrict__ qf, const float* __restrict__ mu,
               const float* __restrict__ rs, const float* __restrict__ g,
               const float* __restrict__ b, unsigned short* __restrict__ qn) {
    int i = blockIdx.x * 256 + threadIdx.x;
    int c = i & (DQ_ - 1);
    qn[i] = f2bf((qf[i] - mu[c]) * rs[c] * g[c] + b[c]);
}

// ---------------- fused top-k ----------------
__global__ __launch_bounds__(256)
void topk_kernel(const float* __restrict__ dots, float* __restrict__ fs, int* __restrict__ vi) {
    static const unsigned short tab[128] = {
        0,1,2,3,4,5,6,7,8,9,10,11,12,13,14,15,16,17,18,19,20,21,22,23,24,25,26,27,28,29,30,31,
        32,33,34,35,36,37,38,39,40,41,42,43,44,45,46,47,
        64,65,66,67,68,69,70,71,72,73,
        96,97,98,99,100,101,102,103,
        128,129,130,131,132,133,
        160,161,162,163,164,
        192,193,194,195,
        224,225,226,227,
        256,257,258,
        288,289,290,
        320,321, 352,353, 384,385, 416,417, 448,449, 480,481,
        512,544,576,608,640,672,704,736,768,800,832,864,896,928,960,992,
        0xFFFF,0xFFFF,0xFFFF,0xFFFF,0xFFFF,0xFFFF,0xFFFF,0xFFFF,0xFFFF
    };
    __shared__ float sv[4][64];
    __shared__ int   sidx[4][64];
    int tid = threadIdx.x, wv = tid >> 6, lane = tid & 63;
    long task = (long)blockIdx.x * 4 + wv;
    const float* dbase = dots + (task >> 2) * 2048 + (task & 3) * 512;

#pragma unroll 1
    for (int half = 0; half < 2; ++half) {
        const float* d = dbase + half * 256;
        float v0 = d[lane], v1 = d[lane + 64], v2 = d[lane + 128], v3 = d[lane + 192];
#pragma unroll 1
        for (int t = 0; t < 32; ++t) {
            float bm = v0; int ba = 0;
            if (v1 > bm) { bm = v1; ba = 1; }
            if (v2 > bm) { bm = v2; ba = 2; }
            if (v3 > bm) { bm = v3; ba = 3; }
            float wm = bm;
#pragma unroll
            for (int o = 32; o >= 1; o >>= 1) wm = fmaxf(wm, __shfl_xor(wm, o));
            unsigned long long msk = __ballot(bm == wm);
            int owner = (int)__builtin_ctzll(msk);
            if (lane == owner) {
                sv[wv][half * 32 + t] = wm;
                sidx[wv][half * 32 + t] = ba * 64 + lane;
                if (ba == 0) v0 = -1e30f;
                else if (ba == 1) v1 = -1e30f;
                else if (ba == 2) v2 = -1e30f;
                else v3 = -1e30f;
            }
        }
    }
    __syncthreads();

    unsigned short t0 = tab[lane], t1 = tab[lane + 64];
    float v0 = -1e30f, v1 = -1e30f;
    int id0 = 0, id1 = 0;
    {
        int i = t0 >> 5, j = t0 & 31;
        v0 = sv[wv][i] + sv[wv][32 + j];
        id0 = sidx[wv][i] * NK_ + sidx[wv][32 + j];
    }
    if (t1 != 0xFFFF) {
        int i = t1 >> 5, j = t1 & 31;
        v1 = sv[wv][i] + sv[wv][32 + j];
        id1 = sidx[wv][i] * NK_ + sidx[wv][32 + j];
    }

    float* fo = fs + task * 32;
    int*   vo = vi + task * 32;
#pragma unroll 1
    for (int t = 0; t < 32; ++t) {
        float bm = v0; int sel = 0;
        if (v1 > bm) { bm = v1; sel = 1; }
        float wm = bm;
#pragma unroll
        for (int o = 32; o >= 1; o >>= 1) wm = fmaxf(wm, __shfl_xor(wm, o));
        unsigned long long msk = __ballot(bm == wm);
        int owner = (int)__builtin_ctzll(msk);
        if (lane == owner) {
            fo[t] = wm;
            vo[t] = sel ? id1 : id0;
            if (sel) v1 = -1e30f; else v0 = -1e30f;
        }
    }
}

// ---------------- softmax + gather(bf16 table) + residual ----------------
// 384 threads = 4 row-slots x 96 chunks of 8 bf16 (16B/lane).
__global__ __launch_bounds__(384)
void pkm_out_bf16(const float* __restrict__ fs, const int* __restrict__ vi,
                  const unsigned short* __restrict__ valsb, const float* __restrict__ x1,
                  float* __restrict__ outp) {
    int n = blockIdx.x, tid = threadIdx.x;
    __shared__ float w[128];
    __shared__ int   rows[128];
    __shared__ float red[3 * 768];
    if (tid < 128) {
        float e = fs[(long)n * 128 + tid];
        rows[tid] = vi[(long)n * 128 + tid];
        float m = e;
#pragma unroll
        for (int o = 16; o >= 1; o >>= 1) m = fmaxf(m, __shfl_xor(m, o));
        float ex = __expf(e - m);
        float s = ex;
#pragma unroll
        for (int o = 16; o >= 1; o >>= 1) s += __shfl_xor(s, o);
        w[tid] = ex / s;
    }
    __syncthreads();
    int slot = tid / 96, chunk = tid % 96;
    float a0=0.f,a1=0.f,a2=0.f,a3=0.f,a4=0.f,a5=0.f,a6=0.f,a7=0.f;
#pragma unroll 4
    for (int e = 0; e < 32; ++e) {
        int er = e * 4 + slot;
        float wgt = w[er];
        long ro = (long)rows[er] * D_;
        bf16x8 v = *(const bf16x8*)(valsb + ro + chunk * 8);
        a0 += wgt * bf2f((unsigned short)v[0]); a1 += wgt * bf2f((unsigned short)v[1]);
        a2 += wgt * bf2f((unsigned short)v[2]); a3 += wgt * bf2f((unsigned short)v[3]);
        a4 += wgt * bf2f((unsigned short)v[4]); a5 += wgt * bf2f((unsigned short)v[5]);
        a6 += wgt * bf2f((unsigned short)v[6]); a7 += wgt * bf2f((unsigned short)v[7]);
    }
    if (slot > 0) {
        float* rp = &red[(slot - 1) * 768 + chunk * 8];
        rp[0]=a0; rp[1]=a1; rp[2]=a2; rp[3]=a3; rp[4]=a4; rp[5]=a5; rp[6]=a6; rp[7]=a7;
    }
    __syncthreads();
    if (slot == 0) {
        long o = (long)n * D_ + chunk * 8;
        const float* r0 = &red[chunk * 8];
        const float* r1 = &red[768 + chunk * 8];
        const float* r2 = &red[1536 + chunk * 8];
        f32x4 xa = *(const f32x4*)(x1 + o);
        f32x4 xb = *(const f32x4*)(x1 + o + 4);
        f32x4 o1 = { a0 + r0[0] + r1[0] + r2[0] + xa[0], a1 + r0[1] + r1[1] + r2[1] + xa[1],
                     a2 + r0[2] + r1[2] + r2[2] + xa[2], a3 + r0[3] + r1[3] + r2[3] + xa[3] };
        f32x4 o2 = { a4 + r0[4] + r1[4] + r2[4] + xb[0], a5 + r0[5] + r1[5] + r2[5] + xb[1],
                     a6 + r0[6] + r1[6] + r2[6] + xb[2], a7 + r0[7] + r1[7] + r2[7] + xb[3] };
        *(f32x4*)(outp + o) = o1;
        *(f32x4*)(outp + o + 4) = o2;
    }
}

// ---------------- fallback: f32-table gather ----------------
__global__ __launch_bounds__(384)
void pkm_out_f32(const float* __restrict__ fs, const int* __restrict__ vi,
                 const float* __restrict__ values, const float* __restrict__ x1,
                 float* __restrict__ outp) {
    int n = blockIdx.x, tid = threadIdx.x;
    __shared__ float w[128];
    __shared__ int   rows[128];
    __shared__ float red[768];
    if (tid < 128) {
        float e = fs[(long)n * 128 + tid];
        rows[tid] = vi[(long)n * 128 + tid];
        float m = e;
#pragma unroll
        for (int o = 16; o >= 1; o >>= 1) m = fmaxf(m, __shfl_xor(m, o));
        float ex = __expf(e - m);
        float s = ex;
#pragma unroll
        for (int o = 16; o >= 1; o >>= 1) s += __shfl_xor(s, o);
        w[tid] = ex / s;
    }
    __syncthreads();
    int slot = tid / 192, chunk = tid % 192;
    float a0 = 0.f, a1 = 0.f, a2 = 0.f, a3 = 0.f;
#pragma unroll 4
    for (int e = 0; e < 64; ++e) {
        int er = e * 2 + slot;
        float wgt = w[er];
        long ro = (long)rows[er] * D_;
        f32x4 v = *(const f32x4*)(values + ro + chunk * 4);
        a0 += wgt * v[0]; a1 += wgt * v[1]; a2 += wgt * v[2]; a3 += wgt * v[3];
    }
    if (slot == 1) {
        f32x4 t = {a0, a1, a2, a3};
        *(f32x4*)&red[chunk * 4] = t;
    }
    __syncthreads();
    if (slot == 0) {
        f32x4 o = *(const f32x4*)&red[chunk * 4];
        f32x4 xr = *(const f32x4*)(x1 + (long)n * D_ + chunk * 4);
        o[0] += a0 + xr[0]; o[1] += a1 + xr[1]; o[2] += a2 + xr[2]; o[3] += a3 + xr[3];
        *(f32x4*)(outp + (long)n * D_ + chunk * 4) = o;
    }
}

extern "C" void kernel_launch(void* const* d_in, const int* in_sizes, int n_in,
                              void* d_out, int out_size, void* d_ws, size_t ws_size,
                              hipStream_t stream) {
    const float* x    = (const float*)d_in[0];
    const float* wq   = (const float*)d_in[1];
    const float* bq   = (const float*)d_in[2];
    const float* wk   = (const float*)d_in[3];
    const float* bk   = (const float*)d_in[4];
    const float* wv   = (const float*)d_in[5];
    const float* bv   = (const float*)d_in[6];
    const float* wo   = (const float*)d_in[7];
    const float* bo   = (const float*)d_in[8];
    const float* ln1g = (const float*)d_in[9];
    const float* ln1b = (const float*)d_in[10];
    const float* ln2g = (const float*)d_in[11];
    const float* ln2b = (const float*)d_in[12];
    const float* pwq  = (const float*)d_in[13];
    const float* bng  = (const float*)d_in[14];
    const float* bnb  = (const float*)d_in[15];
    const float* keys = (const float*)d_in[16];
    const float* vals = (const float*)d_in[17];
    float* out = (float*)d_out;

    char* p = (char*)d_ws;
    auto alloc = [&](size_t bytes) -> char* {
        char* r = p; p += (bytes + 255) & ~(size_t)255; return r;
    };
    unsigned short* wqkvT = (unsigned short*)alloc((size_t)3 * D_ * D_ * 2);
    unsigned short* woT   = (unsigned short*)alloc((size_t)D_ * D_ * 2);
    unsigned short* pwqT  = (unsigned short*)alloc((size_t)D_ * DQ_ * 2);
    unsigned short* keyB  = (unsigned short*)alloc((size_t)PH_ * NK_ * 2 * DHK_ * 2);
    unsigned short* h1    = (unsigned short*)alloc((size_t)NT * D_ * 2);
    unsigned short* qkvB  = (unsigned short*)alloc((size_t)NT * QKVLD * 2);
    unsigned short* aout  = (unsigned short*)alloc((size_t)NT * D_ * 2);
    float* x1             = (float*)alloc((size_t)NT * D_ * 4);
    unsigned short* h2    = (unsigned short*)alloc((size_t)NT * D_ * 2);
    float* qf             = (float*)alloc((size_t)NT * DQ_ * 4);
    float* pS             = (float*)alloc((size_t)8 * DQ_ * 4);
    float* pSS            = (float*)alloc((size_t)8 * DQ_ * 4);
    float* mu             = (float*)alloc((size_t)DQ_ * 4);
    float* rs             = (float*)alloc((size_t)DQ_ * 4);
    unsigned short* qnB   = (unsigned short*)alloc((size_t)NT * DQ_ * 2);
    float* dots           = (float*)alloc((size_t)NT * 2048 * 4);
    float* fsb            = (float*)alloc((size_t)NT * PH_ * 32 * 4);
    int*   vib            = (int*)alloc((size_t)NT * PH_ * 32 * 4);

    // bf16 values table if workspace allows (~100.7 MB more)
    size_t used = (size_t)(p - (char*)d_ws);
    size_t vbytes = (size_t)NK_ * NK_ * D_ * 2;
    bool useBf = (used + vbytes + 256) <= ws_size;
    unsigned short* valsb = nullptr;
    if (useBf) valsb = (unsigned short*)alloc(vbytes);

    // weight prep
    transpose_kernel<<<dim3(24, 32, 5), dim3(32, 8), 0, stream>>>(wq, wk, wv, wo, pwq, wqkvT, woT, pwqT);
    conv_kernel<<<(PH_ * NK_ * 2 * DHK_) / 256, 256, 0, stream>>>(keys, keyB, PH_ * NK_ * 2 * DHK_);
    if (useBf)
        convv_kernel<<<(NK_ * NK_ * D_) / (256 * 8), 256, 0, stream>>>(vals, valsb);

    // LN1
    ln_kernel<<<NT, 256, 0, stream>>>(x, ln1g, ln1b, h1);
    // merged QKV GEMM -> qkvB [2048][2304] bf16 (64^2 tile, 1152 blocks)
    gemm_kernel<<<dim3(32, 36), 256, 0, stream>>>(h1, D_, wqkvT, D_, bq, bk, bv, nullptr, nullptr, qkvB, QKVLD, D_, 2);
    // attention (MFMA flash)
    attn_mfma_kernel<<<dim3(B_ * H_, T_ / 64), 256, 0, stream>>>(qkvB, aout);
    // output projection + residual
    gemm_kernel<<<dim3(32, 12), 256, 0, stream>>>(aout, D_, woT, D_, bo, nullptr, nullptr, x, x1, nullptr, D_, D_, 0);
    // LN2 + PKM query
    ln_kernel<<<NT, 256, 0, stream>>>(x1, ln2g, ln2b, h2);
    gemm_kernel<<<dim3(32, 16), 256, 0, stream>>>(h2, D_, pwqT, D_, nullptr, nullptr, nullptr, nullptr, qf, nullptr, DQ_, D_, 0);
    // BatchNorm
    bn_part<<<dim3(8, 4), 256, 0, stream>>>(qf, pS, pSS);
    bn_fin<<<4, 256, 0, stream>>>(pS, pSS, mu, rs);
    qn_kernel<<<(NT * DQ_) / 256, 256, 0, stream>>>(qf, mu, rs, bng, bnb, qnB);
    // dots: 8 batched GEMMs via blockIdx.z
    gemm_kernel<<<dim3(32, 4, 8), 256, 0, stream>>>(qnB, DQ_, keyB, 256, nullptr, nullptr, nullptr, nullptr, dots, nullptr, 2048, DHK_, 1);
    // fused top-k
    topk_kernel<<<(NT * PH_) / 4, 256, 0, stream>>>(dots, fsb, vib);
    // softmax + gather + residual
    if (useBf)
        pkm_out_bf16<<<NT, 384, 0, stream>>>(fsb, vib, valsb, x1, out);
    else
        pkm_out_f32<<<NT, 384, 0, stream>>>(fsb, vib, vals, x1, out);
}

// Round 8
// 318.901 us; speedup vs baseline: 1.1297x; 1.0103x over previous
//
#include <hip/hip_runtime.h>
#include <hip/hip_bf16.h>

#define B_  2
#define T_  1024
#define D_  768
#define H_  12
#define NT  2048        // B*T
#define DQ_ 1024
#define PH_ 4
#define NK_ 256
#define TK_ 32
#define DHK_ 128
#define QKVLD 2304      // merged QKV row stride
#define ATTN_BLKS 384   // 24 bh x 16 q-tiles
#define CONV_BLKS 1024  // converter blocks fused into attn launch

typedef __attribute__((ext_vector_type(8))) short bf16x8;
typedef __attribute__((ext_vector_type(4))) float f32x4;

static __device__ __forceinline__ unsigned short f2bf(float f) {
    union { float f; unsigned u; } c; c.f = f;
    unsigned r = (c.u + 0x7fffu + ((c.u >> 16) & 1u)) >> 16;
    return (unsigned short)r;
}

static __device__ __forceinline__ float bf2f(unsigned short s) {
    union { unsigned u; float f; } c; c.u = ((unsigned)s) << 16;
    return c.f;
}

// ---------------- batched transpose+convert: 5 weight matrices in one launch ----------------
__global__ void transpose_kernel(const float* __restrict__ wq, const float* __restrict__ wk,
                                 const float* __restrict__ wv, const float* __restrict__ wo,
                                 const float* __restrict__ pwq,
                                 unsigned short* __restrict__ wqkvT,
                                 unsigned short* __restrict__ woT,
                                 unsigned short* __restrict__ pwqT) {
    __shared__ float t[32][33];
    int z = blockIdx.z;
    const float* W; unsigned short* Wt; int N;
    if (z == 0)      { W = wq;  Wt = wqkvT;              N = 768; }
    else if (z == 1) { W = wk;  Wt = wqkvT + 589824;     N = 768; }
    else if (z == 2) { W = wv;  Wt = wqkvT + 2 * 589824; N = 768; }
    else if (z == 3) { W = wo;  Wt = woT;                N = 768; }
    else             { W = pwq; Wt = pwqT;               N = 1024; }
    int k0 = blockIdx.x * 32, n0 = blockIdx.y * 32;
    if (n0 >= N) return;
    int tx = threadIdx.x, ty = threadIdx.y;
#pragma unroll
    for (int i = 0; i < 4; ++i)
        t[ty + 8 * i][tx] = W[(long)(k0 + ty + 8 * i) * N + n0 + tx];
    __syncthreads();
#pragma unroll
    for (int i = 0; i < 4; ++i)
        Wt[(long)(n0 + ty + 8 * i) * 768 + k0 + tx] = f2bf(t[tx][ty + 8 * i]);
}

// ---------------- elementwise f32 -> bf16 (keys) ----------------
__global__ void conv_kernel(const float* __restrict__ in, unsigned short* __restrict__ out, int n) {
    int i = blockIdx.x * blockDim.x + threadIdx.x;
    if (i < n) out[i] = f2bf(in[i]);
}

// ---------------- LayerNorm: x f32 [rows][768] -> bf16 ----------------
__global__ __launch_bounds__(256)
void ln_kernel(const float* __restrict__ x, const float* __restrict__ g,
               const float* __restrict__ b, unsigned short* __restrict__ out) {
    int row = blockIdx.x, tid = threadIdx.x;
    const float* xr = x + (long)row * D_;
    float v0 = xr[tid], v1 = xr[tid + 256], v2 = xr[tid + 512];
    float s = v0 + v1 + v2, ss = v0 * v0 + v1 * v1 + v2 * v2;
#pragma unroll
    for (int o = 1; o < 64; o <<= 1) { s += __shfl_xor(s, o); ss += __shfl_xor(ss, o); }
    __shared__ float ps[4], pss[4];
    int wid = tid >> 6, lane = tid & 63;
    if (lane == 0) { ps[wid] = s; pss[wid] = ss; }
    __syncthreads();
    s = ps[0] + ps[1] + ps[2] + ps[3];
    ss = pss[0] + pss[1] + pss[2] + pss[3];
    float mean = s * (1.f / D_);
    float var = ss * (1.f / D_) - mean * mean;
    float rs = rsqrtf(var + 1e-5f);
    unsigned short* orow = out + (long)row * D_;
    orow[tid]       = f2bf((v0 - mean) * rs * g[tid]       + b[tid]);
    orow[tid + 256] = f2bf((v1 - mean) * rs * g[tid + 256] + b[tid + 256]);
    orow[tid + 512] = f2bf((v2 - mean) * rs * g[tid + 512] + b[tid + 512]);
}

// ---------------- MFMA GEMM: C[M,N] = A[M,K](bf16,lda) @ Bt[N,K](bf16,ldb)^T ----------------
// 64x64 tile, 4 waves, BK=32.
// zmode 1: dots batching over blockIdx.z. zmode 2: merged QKV (bias segment select).
__global__ __launch_bounds__(256)
void gemm_kernel(const unsigned short* __restrict__ A, int lda,
                 const unsigned short* __restrict__ Bt, int ldb,
                 const float* __restrict__ bias,
                 const float* __restrict__ bias2,
                 const float* __restrict__ bias3,
                 const float* __restrict__ res,
                 float* __restrict__ outF,
                 unsigned short* __restrict__ outB,
                 int ldc, int K, int zmode) {
    if (zmode == 1) {
        int z = blockIdx.z, ph = z >> 1, half = z & 1;
        A    += half * 512 + ph * 128;
        Bt   += ph * 65536 + half * 128;
        outF += ph * 512 + half * 256;
    }
    const int tid = threadIdx.x;
    const int w = tid >> 6, lane = tid & 63;
    const int ls = lane & 15, g = lane >> 4;
    const int m0 = blockIdx.x * 64, n0 = blockIdx.y * 64;

    __shared__ unsigned short As[64][40];
    __shared__ unsigned short Bs[64][40];

    f32x4 acc[4];
#pragma unroll
    for (int c = 0; c < 4; ++c) acc[c] = (f32x4){0.f, 0.f, 0.f, 0.f};

    const int lrow = tid >> 2, lseg = tid & 3;
    const unsigned short* gA = A + (long)(m0 + lrow) * lda + lseg * 8;
    const unsigned short* gB = Bt + (long)(n0 + lrow) * ldb + lseg * 8;

    for (int kt = 0; kt < K; kt += 32) {
        __syncthreads();
        *(int4*)&As[lrow][lseg * 8] = *(const int4*)(gA + kt);
        *(int4*)&Bs[lrow][lseg * 8] = *(const int4*)(gB + kt);
        __syncthreads();
        bf16x8 bfr = *(const bf16x8*)&Bs[w * 16 + ls][g * 8];
#pragma unroll
        for (int c = 0; c < 4; ++c) {
            bf16x8 afr = *(const bf16x8*)&As[c * 16 + ls][g * 8];
            acc[c] = __builtin_amdgcn_mfma_f32_16x16x32_bf16(afr, bfr, acc[c], 0, 0, 0);
        }
    }
#pragma unroll
    for (int c = 0; c < 4; ++c) {
#pragma unroll
        for (int r = 0; r < 4; ++r) {
            int row = m0 + c * 16 + g * 4 + r;
            int col = n0 + w * 16 + ls;
            float v = acc[c][r];
            if (bias) {
                const float* bp = bias; int cc = col;
                if (zmode == 2) {
                    int sel = col >= 1536 ? 2 : (col >= 768 ? 1 : 0);
                    bp = sel == 0 ? bias : (sel == 1 ? bias2 : bias3);
                    cc = col - sel * 768;
                }
                v += bp[cc];
            }
            long off = (long)row * ldc + col;
            if (res)  v += res[off];
            if (outF) outF[off] = v;
            if (outB) outB[off] = f2bf(v);
        }
    }
}

// ---------------- MFMA flash attention FUSED with values-table bf16 conversion ----------------
// blocks [0, ATTN_BLKS): attention (bh = bid>>4, q-tile = bid&15)
// blocks [ATTN_BLKS, ATTN_BLKS+CONV_BLKS): grid-stride convert vals f32 -> bf16
// The converter streams HBM on CUs the low-occupancy attention leaves idle.
__global__ __launch_bounds__(256)
void attn_conv_kernel(const unsigned short* __restrict__ qkv,
                      unsigned short* __restrict__ outg,
                      const float* __restrict__ vals,
                      unsigned short* __restrict__ valsb,
                      int doConv) {
    int tid = threadIdx.x;
    if (blockIdx.x >= ATTN_BLKS) {
        if (!doConv) return;
        long idx = ((long)(blockIdx.x - ATTN_BLKS) * 256 + tid) * 8;
        const long stride = (long)CONV_BLKS * 256 * 8;     // 2,097,152 elems
#pragma unroll 2
        for (int it = 0; it < 24; ++it) {                  // 24 * 2097152 = 50,331,648 = NK*NK*D
            f32x4 a = *(const f32x4*)(vals + idx);
            f32x4 b = *(const f32x4*)(vals + idx + 4);
            bf16x8 r;
#pragma unroll
            for (int j = 0; j < 4; ++j) { r[j] = (short)f2bf(a[j]); r[4 + j] = (short)f2bf(b[j]); }
            *(bf16x8*)(valsb + idx) = r;
            idx += stride;
        }
        return;
    }

    int bh = blockIdx.x >> 4, bb = bh / H_, hh = bh % H_;
    int q0 = (blockIdx.x & 15) * 64;
    int wv = tid >> 6, lane = tid & 63;
    int ls = lane & 15, g = lane >> 4;

    __shared__ unsigned short Klds[128 * 64];
    __shared__ unsigned short Vlds[64 * 128];
    __shared__ unsigned short Plds[4][16 * 128];

    const unsigned short* qrow = qkv + (long)(bb * T_ + q0 + wv * 16 + ls) * QKVLD + hh * 64 + g * 8;
    bf16x8 qf0 = *(const bf16x8*)qrow;
    bf16x8 qf1 = *(const bf16x8*)(qrow + 32);

    f32x4 o_acc[4];
#pragma unroll
    for (int nf = 0; nf < 4; ++nf) o_acc[nf] = (f32x4){0.f, 0.f, 0.f, 0.f};
    float mrun[4] = {-1e30f, -1e30f, -1e30f, -1e30f};
    float lrun[4] = {0.f, 0.f, 0.f, 0.f};

    char* pbase = (char*)&Plds[wv][0];

    for (int kt = 0; kt < T_ / 128; ++kt) {
        int kvb = kt * 128;
        __syncthreads();
#pragma unroll
        for (int i = 0; i < 4; ++i) {
            int c = tid + i * 256;
            int kv = c >> 3, dc = c & 7;
            bf16x8 kd = *(const bf16x8*)(qkv + (long)(bb * T_ + kvb + kv) * QKVLD + 768 + hh * 64 + dc * 8);
            *(bf16x8*)((char*)Klds + ((kv * 128 + dc * 16) ^ ((kv & 7) << 4))) = kd;
        }
        {
            int d0 = (tid & 7) * 8, kvq = tid >> 3;
            const unsigned short* vb = qkv + (long)(bb * T_ + kvb + kvq * 4) * QKVLD + 1536 + hh * 64 + d0;
            bf16x8 r0 = *(const bf16x8*)(vb);
            bf16x8 r1 = *(const bf16x8*)(vb + QKVLD);
            bf16x8 r2 = *(const bf16x8*)(vb + 2 * QKVLD);
            bf16x8 r3 = *(const bf16x8*)(vb + 3 * QKVLD);
#pragma unroll
            for (int j = 0; j < 8; ++j) {
                unsigned lo = (unsigned)(unsigned short)r0[j] | ((unsigned)(unsigned short)r1[j] << 16);
                unsigned hi = (unsigned)(unsigned short)r2[j] | ((unsigned)(unsigned short)r3[j] << 16);
                int d = d0 + j;
                *(uint2*)((char*)Vlds + ((d * 256 + kvq * 8) ^ ((d & 7) << 4))) = make_uint2(lo, hi);
            }
        }
        __syncthreads();

        f32x4 sa[8];
#pragma unroll
        for (int f = 0; f < 8; ++f) sa[f] = (f32x4){0.f, 0.f, 0.f, 0.f};
#pragma unroll
        for (int f = 0; f < 8; ++f) {
            int kv = f * 16 + ls;
            bf16x8 b0 = *(const bf16x8*)((char*)Klds + ((kv * 128 + g * 16) ^ ((kv & 7) << 4)));
            bf16x8 b1 = *(const bf16x8*)((char*)Klds + ((kv * 128 + 64 + g * 16) ^ ((kv & 7) << 4)));
            sa[f] = __builtin_amdgcn_mfma_f32_16x16x32_bf16(qf0, b0, sa[f], 0, 0, 0);
            sa[f] = __builtin_amdgcn_mfma_f32_16x16x32_bf16(qf1, b1, sa[f], 0, 0, 0);
        }

        float pw[8][4];
#pragma unroll
        for (int f = 0; f < 8; ++f)
#pragma unroll
            for (int r = 0; r < 4; ++r) pw[f][r] = sa[f][r] * 0.125f;
        float nm[4], fac[4];
#pragma unroll
        for (int r = 0; r < 4; ++r) {
            float m = pw[0][r];
#pragma unroll
            for (int f = 1; f < 8; ++f) m = fmaxf(m, pw[f][r]);
            m = fmaxf(m, __shfl_xor(m, 1));
            m = fmaxf(m, __shfl_xor(m, 2));
            m = fmaxf(m, __shfl_xor(m, 4));
            m = fmaxf(m, __shfl_xor(m, 8));
            nm[r] = fmaxf(mrun[r], m);
            fac[r] = __expf(mrun[r] - nm[r]);
            mrun[r] = nm[r];
        }
#pragma unroll
        for (int r = 0; r < 4; ++r) {
            float s = 0.f;
#pragma unroll
            for (int f = 0; f < 8; ++f) { float e = __expf(pw[f][r] - nm[r]); pw[f][r] = e; s += e; }
            s += __shfl_xor(s, 1); s += __shfl_xor(s, 2);
            s += __shfl_xor(s, 4); s += __shfl_xor(s, 8);
            lrun[r] = lrun[r] * fac[r] + s;
#pragma unroll
            for (int nf = 0; nf < 4; ++nf) o_acc[nf][r] *= fac[r];
        }

#pragma unroll
        for (int f = 0; f < 8; ++f)
#pragma unroll
            for (int r = 0; r < 4; ++r) {
                int qr = g * 4 + r, col = ls + 16 * f;
                *(unsigned short*)(pbase + ((qr * 256 + col * 2) ^ ((qr & 7) << 4))) = f2bf(pw[f][r]);
            }

#pragma unroll
        for (int ks = 0; ks < 4; ++ks) {
            bf16x8 pa = *(const bf16x8*)(pbase + ((ls * 256 + ks * 64 + g * 16) ^ ((ls & 7) << 4)));
#pragma unroll
            for (int nf = 0; nf < 4; ++nf) {
                int d = nf * 16 + ls;
                bf16x8 bv = *(const bf16x8*)((char*)Vlds + ((d * 256 + ks * 64 + g * 16) ^ ((d & 7) << 4)));
                o_acc[nf] = __builtin_amdgcn_mfma_f32_16x16x32_bf16(pa, bv, o_acc[nf], 0, 0, 0);
            }
        }
    }

    float inv[4];
#pragma unroll
    for (int r = 0; r < 4; ++r) inv[r] = 1.f / lrun[r];
#pragma unroll
    for (int nf = 0; nf < 4; ++nf)
#pragma unroll
        for (int r = 0; r < 4; ++r) {
            long row = bb * T_ + q0 + wv * 16 + g * 4 + r;
            outg[row * D_ + hh * 64 + nf * 16 + ls] = f2bf(o_acc[nf][r] * inv[r]);
        }
}

// ---------------- BatchNorm over tokens (deterministic two-stage) ----------------
__global__ __launch_bounds__(256)
void bn_part(const float* __restrict__ qf, float* __restrict__ pS, float* __restrict__ pSS) {
    int c = blockIdx.y * 256 + threadIdx.x;
    int r0 = blockIdx.x * 256;
    float s = 0.f, ss = 0.f;
    for (int r = 0; r < 256; ++r) {
        float v = qf[(long)(r0 + r) * DQ_ + c];
        s += v; ss += v * v;
    }
    pS[blockIdx.x * DQ_ + c] = s;
    pSS[blockIdx.x * DQ_ + c] = ss;
}

__global__ __launch_bounds__(256)
void bn_fin(const float* __restrict__ pS, const float* __restrict__ pSS,
            float* __restrict__ mu, float* __restrict__ rs) {
    int c = blockIdx.x * 256 + threadIdx.x;
    float s = 0.f, ss = 0.f;
#pragma unroll
    for (int i = 0; i < 8; ++i) { s += pS[i * DQ_ + c]; ss += pSS[i * DQ_ + c]; }
    float m = s * (1.f / NT);
    float var = ss * (1.f / NT) - m * m;
    mu[c] = m;
    rs[c] = rsqrtf(var + 1e-5f);
}

__global__ __launch_bounds__(256)
void qn_kernel(const float* __restrict__ qf, const float* __restrict__ mu,
               const float* __restrict__ rs, const float* __restrict__ g,
               const float* __restrict__ b, unsigned short* __restrict__ qn) {
    int i = blockIdx.x * 256 + threadIdx.x;
    int c = i & (DQ_ - 1);
    qn[i] = f2bf((qf[i] - mu[c]) * rs[c] * g[c] + b[c]);
}

// ---------------- fused top-k ----------------
__global__ __launch_bounds__(256)
void topk_kernel(const float* __restrict__ dots, float* __restrict__ fs, int* __restrict__ vi) {
    static const unsigned short tab[128] = {
        0,1,2,3,4,5,6,7,8,9,10,11,12,13,14,15,16,17,18,19,20,21,22,23,24,25,26,27,28,29,30,31,
        32,33,34,35,36,37,38,39,40,41,42,43,44,45,46,47,
        64,65,66,67,68,69,70,71,72,73,
        96,97,98,99,100,101,102,103,
        128,129,130,131,132,133,
        160,161,162,163,164,
        192,193,194,195,
        224,225,226,227,
        256,257,258,
        288,289,290,
        320,321, 352,353, 384,385, 416,417, 448,449, 480,481,
        512,544,576,608,640,672,704,736,768,800,832,864,896,928,960,992,
        0xFFFF,0xFFFF,0xFFFF,0xFFFF,0xFFFF,0xFFFF,0xFFFF,0xFFFF,0xFFFF
    };
    __shared__ float sv[4][64];
    __shared__ int   sidx[4][64];
    int tid = threadIdx.x, wv = tid >> 6, lane = tid & 63;
    long task = (long)blockIdx.x * 4 + wv;
    const float* dbase = dots + (task >> 2) * 2048 + (task & 3) * 512;

#pragma unroll 1
    for (int half = 0; half < 2; ++half) {
        const float* d = dbase + half * 256;
        float v0 = d[lane], v1 = d[lane + 64], v2 = d[lane + 128], v3 = d[lane + 192];
#pragma unroll 1
        for (int t = 0; t < 32; ++t) {
            float bm = v0; int ba = 0;
            if (v1 > bm) { bm = v1; ba = 1; }
            if (v2 > bm) { bm = v2; ba = 2; }
            if (v3 > bm) { bm = v3; ba = 3; }
            float wm = bm;
#pragma unroll
            for (int o = 32; o >= 1; o >>= 1) wm = fmaxf(wm, __shfl_xor(wm, o));
            unsigned long long msk = __ballot(bm == wm);
            int owner = (int)__builtin_ctzll(msk);
            if (lane == owner) {
                sv[wv][half * 32 + t] = wm;
                sidx[wv][half * 32 + t] = ba * 64 + lane;
                if (ba == 0) v0 = -1e30f;
                else if (ba == 1) v1 = -1e30f;
                else if (ba == 2) v2 = -1e30f;
                else v3 = -1e30f;
            }
        }
    }
    __syncthreads();

    unsigned short t0 = tab[lane], t1 = tab[lane + 64];
    float v0 = -1e30f, v1 = -1e30f;
    int id0 = 0, id1 = 0;
    {
        int i = t0 >> 5, j = t0 & 31;
        v0 = sv[wv][i] + sv[wv][32 + j];
        id0 = sidx[wv][i] * NK_ + sidx[wv][32 + j];
    }
    if (t1 != 0xFFFF) {
        int i = t1 >> 5, j = t1 & 31;
        v1 = sv[wv][i] + sv[wv][32 + j];
        id1 = sidx[wv][i] * NK_ + sidx[wv][32 + j];
    }

    float* fo = fs + task * 32;
    int*   vo = vi + task * 32;
#pragma unroll 1
    for (int t = 0; t < 32; ++t) {
        float bm = v0; int sel = 0;
        if (v1 > bm) { bm = v1; sel = 1; }
        float wm = bm;
#pragma unroll
        for (int o = 32; o >= 1; o >>= 1) wm = fmaxf(wm, __shfl_xor(wm, o));
        unsigned long long msk = __ballot(bm == wm);
        int owner = (int)__builtin_ctzll(msk);
        if (lane == owner) {
            fo[t] = wm;
            vo[t] = sel ? id1 : id0;
            if (sel) v1 = -1e30f; else v0 = -1e30f;
        }
    }
}

// ---------------- softmax + gather(bf16 table) + residual ----------------
__global__ __launch_bounds__(384)
void pkm_out_bf16(const float* __restrict__ fs, const int* __restrict__ vi,
                  const unsigned short* __restrict__ valsb, const float* __restrict__ x1,
                  float* __restrict__ outp) {
    int n = blockIdx.x, tid = threadIdx.x;
    __shared__ float w[128];
    __shared__ int   rows[128];
    __shared__ float red[3 * 768];
    if (tid < 128) {
        float e = fs[(long)n * 128 + tid];
        rows[tid] = vi[(long)n * 128 + tid];
        float m = e;
#pragma unroll
        for (int o = 16; o >= 1; o >>= 1) m = fmaxf(m, __shfl_xor(m, o));
        float ex = __expf(e - m);
        float s = ex;
#pragma unroll
        for (int o = 16; o >= 1; o >>= 1) s += __shfl_xor(s, o);
        w[tid] = ex / s;
    }
    __syncthreads();
    int slot = tid / 96, chunk = tid % 96;
    float a0=0.f,a1=0.f,a2=0.f,a3=0.f,a4=0.f,a5=0.f,a6=0.f,a7=0.f;
#pragma unroll 4
    for (int e = 0; e < 32; ++e) {
        int er = e * 4 + slot;
        float wgt = w[er];
        long ro = (long)rows[er] * D_;
        bf16x8 v = *(const bf16x8*)(valsb + ro + chunk * 8);
        a0 += wgt * bf2f((unsigned short)v[0]); a1 += wgt * bf2f((unsigned short)v[1]);
        a2 += wgt * bf2f((unsigned short)v[2]); a3 += wgt * bf2f((unsigned short)v[3]);
        a4 += wgt * bf2f((unsigned short)v[4]); a5 += wgt * bf2f((unsigned short)v[5]);
        a6 += wgt * bf2f((unsigned short)v[6]); a7 += wgt * bf2f((unsigned short)v[7]);
    }
    if (slot > 0) {
        float* rp = &red[(slot - 1) * 768 + chunk * 8];
        rp[0]=a0; rp[1]=a1; rp[2]=a2; rp[3]=a3; rp[4]=a4; rp[5]=a5; rp[6]=a6; rp[7]=a7;
    }
    __syncthreads();
    if (slot == 0) {
        long o = (long)n * D_ + chunk * 8;
        const float* r0 = &red[chunk * 8];
        const float* r1 = &red[768 + chunk * 8];
        const float* r2 = &red[1536 + chunk * 8];
        f32x4 xa = *(const f32x4*)(x1 + o);
        f32x4 xb = *(const f32x4*)(x1 + o + 4);
        f32x4 o1 = { a0 + r0[0] + r1[0] + r2[0] + xa[0], a1 + r0[1] + r1[1] + r2[1] + xa[1],
                     a2 + r0[2] + r1[2] + r2[2] + xa[2], a3 + r0[3] + r1[3] + r2[3] + xa[3] };
        f32x4 o2 = { a4 + r0[4] + r1[4] + r2[4] + xb[0], a5 + r0[5] + r1[5] + r2[5] + xb[1],
                     a6 + r0[6] + r1[6] + r2[6] + xb[2], a7 + r0[7] + r1[7] + r2[7] + xb[3] };
        *(f32x4*)(outp + o) = o1;
        *(f32x4*)(outp + o + 4) = o2;
    }
}

// ---------------- fallback: f32-table gather ----------------
__global__ __launch_bounds__(384)
void pkm_out_f32(const float* __restrict__ fs, const int* __restrict__ vi,
                 const float* __restrict__ values, const float* __restrict__ x1,
                 float* __restrict__ outp) {
    int n = blockIdx.x, tid = threadIdx.x;
    __shared__ float w[128];
    __shared__ int   rows[128];
    __shared__ float red[768];
    if (tid < 128) {
        float e = fs[(long)n * 128 + tid];
        rows[tid] = vi[(long)n * 128 + tid];
        float m = e;
#pragma unroll
        for (int o = 16; o >= 1; o >>= 1) m = fmaxf(m, __shfl_xor(m, o));
        float ex = __expf(e - m);
        float s = ex;
#pragma unroll
        for (int o = 16; o >= 1; o >>= 1) s += __shfl_xor(s, o);
        w[tid] = ex / s;
    }
    __syncthreads();
    int slot = tid / 192, chunk = tid % 192;
    float a0 = 0.f, a1 = 0.f, a2 = 0.f, a3 = 0.f;
#pragma unroll 4
    for (int e = 0; e < 64; ++e) {
        int er = e * 2 + slot;
        float wgt = w[er];
        long ro = (long)rows[er] * D_;
        f32x4 v = *(const f32x4*)(values + ro + chunk * 4);
        a0 += wgt * v[0]; a1 += wgt * v[1]; a2 += wgt * v[2]; a3 += wgt * v[3];
    }
    if (slot == 1) {
        f32x4 t = {a0, a1, a2, a3};
        *(f32x4*)&red[chunk * 4] = t;
    }
    __syncthreads();
    if (slot == 0) {
        f32x4 o = *(const f32x4*)&red[chunk * 4];
        f32x4 xr = *(const f32x4*)(x1 + (long)n * D_ + chunk * 4);
        o[0] += a0 + xr[0]; o[1] += a1 + xr[1]; o[2] += a2 + xr[2]; o[3] += a3 + xr[3];
        *(f32x4*)(outp + (long)n * D_ + chunk * 4) = o;
    }
}

extern "C" void kernel_launch(void* const* d_in, const int* in_sizes, int n_in,
                              void* d_out, int out_size, void* d_ws, size_t ws_size,
                              hipStream_t stream) {
    const float* x    = (const float*)d_in[0];
    const float* wq   = (const float*)d_in[1];
    const float* bq   = (const float*)d_in[2];
    const float* wk   = (const float*)d_in[3];
    const float* bk   = (const float*)d_in[4];
    const float* wv   = (const float*)d_in[5];
    const float* bv   = (const float*)d_in[6];
    const float* wo   = (const float*)d_in[7];
    const float* bo   = (const float*)d_in[8];
    const float* ln1g = (const float*)d_in[9];
    const float* ln1b = (const float*)d_in[10];
    const float* ln2g = (const float*)d_in[11];
    const float* ln2b = (const float*)d_in[12];
    const float* pwq  = (const float*)d_in[13];
    const float* bng  = (const float*)d_in[14];
    const float* bnb  = (const float*)d_in[15];
    const float* keys = (const float*)d_in[16];
    const float* vals = (const float*)d_in[17];
    float* out = (float*)d_out;

    char* p = (char*)d_ws;
    auto alloc = [&](size_t bytes) -> char* {
        char* r = p; p += (bytes + 255) & ~(size_t)255; return r;
    };
    unsigned short* wqkvT = (unsigned short*)alloc((size_t)3 * D_ * D_ * 2);
    unsigned short* woT   = (unsigned short*)alloc((size_t)D_ * D_ * 2);
    unsigned short* pwqT  = (unsigned short*)alloc((size_t)D_ * DQ_ * 2);
    unsigned short* keyB  = (unsigned short*)alloc((size_t)PH_ * NK_ * 2 * DHK_ * 2);
    unsigned short* h1    = (unsigned short*)alloc((size_t)NT * D_ * 2);
    unsigned short* qkvB  = (unsigned short*)alloc((size_t)NT * QKVLD * 2);
    unsigned short* aout  = (unsigned short*)alloc((size_t)NT * D_ * 2);
    float* x1             = (float*)alloc((size_t)NT * D_ * 4);
    unsigned short* h2    = (unsigned short*)alloc((size_t)NT * D_ * 2);
    float* qf             = (float*)alloc((size_t)NT * DQ_ * 4);
    float* pS             = (float*)alloc((size_t)8 * DQ_ * 4);
    float* pSS            = (float*)alloc((size_t)8 * DQ_ * 4);
    float* mu             = (float*)alloc((size_t)DQ_ * 4);
    float* rs             = (float*)alloc((size_t)DQ_ * 4);
    unsigned short* qnB   = (unsigned short*)alloc((size_t)NT * DQ_ * 2);
    float* dots           = (float*)alloc((size_t)NT * 2048 * 4);
    float* fsb            = (float*)alloc((size_t)NT * PH_ * 32 * 4);
    int*   vib            = (int*)alloc((size_t)NT * PH_ * 32 * 4);

    // bf16 values table if workspace allows (~100.7 MB more)
    size_t used = (size_t)(p - (char*)d_ws);
    size_t vbytes = (size_t)NK_ * NK_ * D_ * 2;
    bool useBf = (used + vbytes + 256) <= ws_size;
    unsigned short* valsb = nullptr;
    if (useBf) valsb = (unsigned short*)alloc(vbytes);

    // weight prep
    transpose_kernel<<<dim3(24, 32, 5), dim3(32, 8), 0, stream>>>(wq, wk, wv, wo, pwq, wqkvT, woT, pwqT);
    conv_kernel<<<(PH_ * NK_ * 2 * DHK_) / 256, 256, 0, stream>>>(keys, keyB, PH_ * NK_ * 2 * DHK_);

    // LN1
    ln_kernel<<<NT, 256, 0, stream>>>(x, ln1g, ln1b, h1);
    // merged QKV GEMM -> qkvB [2048][2304] bf16
    gemm_kernel<<<dim3(32, 36), 256, 0, stream>>>(h1, D_, wqkvT, D_, bq, bk, bv, nullptr, nullptr, qkvB, QKVLD, D_, 2);
    // attention (MFMA flash) fused with values-table conversion
    attn_conv_kernel<<<ATTN_BLKS + (useBf ? CONV_BLKS : 0), 256, 0, stream>>>(
        qkvB, aout, vals, valsb, useBf ? 1 : 0);
    // output projection + residual
    gemm_kernel<<<dim3(32, 12), 256, 0, stream>>>(aout, D_, woT, D_, bo, nullptr, nullptr, x, x1, nullptr, D_, D_, 0);
    // LN2 + PKM query
    ln_kernel<<<NT, 256, 0, stream>>>(x1, ln2g, ln2b, h2);
    gemm_kernel<<<dim3(32, 16), 256, 0, stream>>>(h2, D_, pwqT, D_, nullptr, nullptr, nullptr, nullptr, qf, nullptr, DQ_, D_, 0);
    // BatchNorm
    bn_part<<<dim3(8, 4), 256, 0, stream>>>(qf, pS, pSS);
    bn_fin<<<4, 256, 0, stream>>>(pS, pSS, mu, rs);
    qn_kernel<<<(NT * DQ_) / 256, 256, 0, stream>>>(qf, mu, rs, bng, bnb, qnB);
    // dots: 8 batched GEMMs via blockIdx.z
    gemm_kernel<<<dim3(32, 4, 8), 256, 0, stream>>>(qnB, DQ_, keyB, 256, nullptr, nullptr, nullptr, nullptr, dots, nullptr, 2048, DHK_, 1);
    // fused top-k
    topk_kernel<<<(NT * PH_) / 4, 256, 0, stream>>>(dots, fsb, vib);
    // softmax + gather + residual
    if (useBf)
        pkm_out_bf16<<<NT, 384, 0, stream>>>(fsb, vib, valsb, x1, out);
    else
        pkm_out_f32<<<NT, 384, 0, stream>>>(fsb, vib, vals, x1, out);
}

// Round 9
// 310.980 us; speedup vs baseline: 1.1585x; 1.0255x over previous
//
#include <hip/hip_runtime.h>
#include <hip/hip_bf16.h>

#define B_  2
#define T_  1024
#define D_  768
#define H_  12
#define NT  2048        // B*T
#define DQ_ 1024
#define PH_ 4
#define NK_ 256
#define TK_ 32
#define DHK_ 128
#define QKVLD 2304      // merged QKV row stride
#define CVHALF 25165824L // half the values table, elements

typedef __attribute__((ext_vector_type(8))) short bf16x8;
typedef __attribute__((ext_vector_type(4))) float f32x4;

static __device__ __forceinline__ unsigned short f2bf(float f) {
    union { float f; unsigned u; } c; c.f = f;
    unsigned r = (c.u + 0x7fffu + ((c.u >> 16) & 1u)) >> 16;
    return (unsigned short)r;
}

static __device__ __forceinline__ float bf2f(unsigned short s) {
    union { unsigned u; float f; } c; c.u = ((unsigned)s) << 16;
    return c.f;
}

// ---------------- batched transpose+convert: 5 weight matrices in one launch ----------------
__global__ void transpose_kernel(const float* __restrict__ wq, const float* __restrict__ wk,
                                 const float* __restrict__ wv, const float* __restrict__ wo,
                                 const float* __restrict__ pwq,
                                 unsigned short* __restrict__ wqkvT,
                                 unsigned short* __restrict__ woT,
                                 unsigned short* __restrict__ pwqT) {
    __shared__ float t[32][33];
    int z = blockIdx.z;
    const float* W; unsigned short* Wt; int N;
    if (z == 0)      { W = wq;  Wt = wqkvT;              N = 768; }
    else if (z == 1) { W = wk;  Wt = wqkvT + 589824;     N = 768; }
    else if (z == 2) { W = wv;  Wt = wqkvT + 2 * 589824; N = 768; }
    else if (z == 3) { W = wo;  Wt = woT;                N = 768; }
    else             { W = pwq; Wt = pwqT;               N = 1024; }
    int k0 = blockIdx.x * 32, n0 = blockIdx.y * 32;
    if (n0 >= N) return;
    int tx = threadIdx.x, ty = threadIdx.y;
#pragma unroll
    for (int i = 0; i < 4; ++i)
        t[ty + 8 * i][tx] = W[(long)(k0 + ty + 8 * i) * N + n0 + tx];
    __syncthreads();
#pragma unroll
    for (int i = 0; i < 4; ++i)
        Wt[(long)(n0 + ty + 8 * i) * 768 + k0 + tx] = f2bf(t[tx][ty + 8 * i]);
}

// ---------------- elementwise f32 -> bf16 (keys) ----------------
__global__ void conv_kernel(const float* __restrict__ in, unsigned short* __restrict__ out, int n) {
    int i = blockIdx.x * blockDim.x + threadIdx.x;
    if (i < n) out[i] = f2bf(in[i]);
}

// ---------------- LayerNorm: x f32 [rows][768] -> bf16 ----------------
__global__ __launch_bounds__(256)
void ln_kernel(const float* __restrict__ x, const float* __restrict__ g,
               const float* __restrict__ b, unsigned short* __restrict__ out) {
    int row = blockIdx.x, tid = threadIdx.x;
    const float* xr = x + (long)row * D_;
    float v0 = xr[tid], v1 = xr[tid + 256], v2 = xr[tid + 512];
    float s = v0 + v1 + v2, ss = v0 * v0 + v1 * v1 + v2 * v2;
#pragma unroll
    for (int o = 1; o < 64; o <<= 1) { s += __shfl_xor(s, o); ss += __shfl_xor(ss, o); }
    __shared__ float ps[4], pss[4];
    int wid = tid >> 6, lane = tid & 63;
    if (lane == 0) { ps[wid] = s; pss[wid] = ss; }
    __syncthreads();
    s = ps[0] + ps[1] + ps[2] + ps[3];
    ss = pss[0] + pss[1] + pss[2] + pss[3];
    float mean = s * (1.f / D_);
    float var = ss * (1.f / D_) - mean * mean;
    float rs = rsqrtf(var + 1e-5f);
    unsigned short* orow = out + (long)row * D_;
    orow[tid]       = f2bf((v0 - mean) * rs * g[tid]       + b[tid]);
    orow[tid + 256] = f2bf((v1 - mean) * rs * g[tid + 256] + b[tid + 256]);
    orow[tid + 512] = f2bf((v2 - mean) * rs * g[tid + 512] + b[tid + 512]);
}

// ---------------- MFMA GEMM: C[M,N] = A[M,K](bf16,lda) @ Bt[N,K](bf16,ldb)^T ----------------
// 64x64 tile, 4 waves, BK=32.
// zmode 1: dots batching over blockIdx.z. zmode 2: merged QKV (bias segment select).
// If cvin != nullptr, blocks with blockIdx.y >= cvy0 instead grid-stride convert
// a CVHALF-element slice of the values table (freeloading on idle CU slots/BW).
__global__ __launch_bounds__(256)
void gemm_kernel(const unsigned short* __restrict__ A, int lda,
                 const unsigned short* __restrict__ Bt, int ldb,
                 const float* __restrict__ bias,
                 const float* __restrict__ bias2,
                 const float* __restrict__ bias3,
                 const float* __restrict__ res,
                 float* __restrict__ outF,
                 unsigned short* __restrict__ outB,
                 int ldc, int K, int zmode,
                 const float* __restrict__ cvin,
                 unsigned short* __restrict__ cvout,
                 long cvbase, int cvy0) {
    if (cvin && (int)blockIdx.y >= cvy0) {
        long stride = (long)(gridDim.y - cvy0) * gridDim.x * 256 * 8;   // elems per sweep
        long idx = cvbase +
            ((long)((blockIdx.y - cvy0) * gridDim.x + blockIdx.x) * 256 + threadIdx.x) * 8;
        long end = cvbase + CVHALF;
#pragma unroll 2
        for (; idx < end; idx += stride) {
            f32x4 a = *(const f32x4*)(cvin + idx);
            f32x4 b = *(const f32x4*)(cvin + idx + 4);
            bf16x8 r;
#pragma unroll
            for (int j = 0; j < 4; ++j) { r[j] = (short)f2bf(a[j]); r[4 + j] = (short)f2bf(b[j]); }
            *(bf16x8*)(cvout + idx) = r;
        }
        return;
    }
    if (zmode == 1) {
        int z = blockIdx.z, ph = z >> 1, half = z & 1;
        A    += half * 512 + ph * 128;
        Bt   += ph * 65536 + half * 128;
        outF += ph * 512 + half * 256;
    }
    const int tid = threadIdx.x;
    const int w = tid >> 6, lane = tid & 63;
    const int ls = lane & 15, g = lane >> 4;
    const int m0 = blockIdx.x * 64, n0 = blockIdx.y * 64;

    __shared__ unsigned short As[64][40];
    __shared__ unsigned short Bs[64][40];

    f32x4 acc[4];
#pragma unroll
    for (int c = 0; c < 4; ++c) acc[c] = (f32x4){0.f, 0.f, 0.f, 0.f};

    const int lrow = tid >> 2, lseg = tid & 3;
    const unsigned short* gA = A + (long)(m0 + lrow) * lda + lseg * 8;
    const unsigned short* gB = Bt + (long)(n0 + lrow) * ldb + lseg * 8;

    for (int kt = 0; kt < K; kt += 32) {
        __syncthreads();
        *(int4*)&As[lrow][lseg * 8] = *(const int4*)(gA + kt);
        *(int4*)&Bs[lrow][lseg * 8] = *(const int4*)(gB + kt);
        __syncthreads();
        bf16x8 bfr = *(const bf16x8*)&Bs[w * 16 + ls][g * 8];
#pragma unroll
        for (int c = 0; c < 4; ++c) {
            bf16x8 afr = *(const bf16x8*)&As[c * 16 + ls][g * 8];
            acc[c] = __builtin_amdgcn_mfma_f32_16x16x32_bf16(afr, bfr, acc[c], 0, 0, 0);
        }
    }
#pragma unroll
    for (int c = 0; c < 4; ++c) {
#pragma unroll
        for (int r = 0; r < 4; ++r) {
            int row = m0 + c * 16 + g * 4 + r;
            int col = n0 + w * 16 + ls;
            float v = acc[c][r];
            if (bias) {
                const float* bp = bias; int cc = col;
                if (zmode == 2) {
                    int sel = col >= 1536 ? 2 : (col >= 768 ? 1 : 0);
                    bp = sel == 0 ? bias : (sel == 1 ? bias2 : bias3);
                    cc = col - sel * 768;
                }
                v += bp[cc];
            }
            long off = (long)row * ldc + col;
            if (res)  v += res[off];
            if (outF) outF[off] = v;
            if (outB) outB[off] = f2bf(v);
        }
    }
}

// ---------------- MFMA flash attention (bf16 in/out, f32 online softmax) ----------------
__global__ __launch_bounds__(256)
void attn_mfma_kernel(const unsigned short* __restrict__ qkv,
                      unsigned short* __restrict__ outg) {
    int bh = blockIdx.x, bb = bh / H_, hh = bh % H_;
    int q0 = blockIdx.y * 64;
    int tid = threadIdx.x, wv = tid >> 6, lane = tid & 63;
    int ls = lane & 15, g = lane >> 4;

    __shared__ unsigned short Klds[128 * 64];
    __shared__ unsigned short Vlds[64 * 128];
    __shared__ unsigned short Plds[4][16 * 128];

    const unsigned short* qrow = qkv + (long)(bb * T_ + q0 + wv * 16 + ls) * QKVLD + hh * 64 + g * 8;
    bf16x8 qf0 = *(const bf16x8*)qrow;
    bf16x8 qf1 = *(const bf16x8*)(qrow + 32);

    f32x4 o_acc[4];
#pragma unroll
    for (int nf = 0; nf < 4; ++nf) o_acc[nf] = (f32x4){0.f, 0.f, 0.f, 0.f};
    float mrun[4] = {-1e30f, -1e30f, -1e30f, -1e30f};
    float lrun[4] = {0.f, 0.f, 0.f, 0.f};

    char* pbase = (char*)&Plds[wv][0];

    for (int kt = 0; kt < T_ / 128; ++kt) {
        int kvb = kt * 128;
        __syncthreads();
#pragma unroll
        for (int i = 0; i < 4; ++i) {
            int c = tid + i * 256;
            int kv = c >> 3, dc = c & 7;
            bf16x8 kd = *(const bf16x8*)(qkv + (long)(bb * T_ + kvb + kv) * QKVLD + 768 + hh * 64 + dc * 8);
            *(bf16x8*)((char*)Klds + ((kv * 128 + dc * 16) ^ ((kv & 7) << 4))) = kd;
        }
        {
            int d0 = (tid & 7) * 8, kvq = tid >> 3;
            const unsigned short* vb = qkv + (long)(bb * T_ + kvb + kvq * 4) * QKVLD + 1536 + hh * 64 + d0;
            bf16x8 r0 = *(const bf16x8*)(vb);
            bf16x8 r1 = *(const bf16x8*)(vb + QKVLD);
            bf16x8 r2 = *(const bf16x8*)(vb + 2 * QKVLD);
            bf16x8 r3 = *(const bf16x8*)(vb + 3 * QKVLD);
#pragma unroll
            for (int j = 0; j < 8; ++j) {
                unsigned lo = (unsigned)(unsigned short)r0[j] | ((unsigned)(unsigned short)r1[j] << 16);
                unsigned hi = (unsigned)(unsigned short)r2[j] | ((unsigned)(unsigned short)r3[j] << 16);
                int d = d0 + j;
                *(uint2*)((char*)Vlds + ((d * 256 + kvq * 8) ^ ((d & 7) << 4))) = make_uint2(lo, hi);
            }
        }
        __syncthreads();

        f32x4 sa[8];
#pragma unroll
        for (int f = 0; f < 8; ++f) sa[f] = (f32x4){0.f, 0.f, 0.f, 0.f};
#pragma unroll
        for (int f = 0; f < 8; ++f) {
            int kv = f * 16 + ls;
            bf16x8 b0 = *(const bf16x8*)((char*)Klds + ((kv * 128 + g * 16) ^ ((kv & 7) << 4)));
            bf16x8 b1 = *(const bf16x8*)((char*)Klds + ((kv * 128 + 64 + g * 16) ^ ((kv & 7) << 4)));
            sa[f] = __builtin_amdgcn_mfma_f32_16x16x32_bf16(qf0, b0, sa[f], 0, 0, 0);
            sa[f] = __builtin_amdgcn_mfma_f32_16x16x32_bf16(qf1, b1, sa[f], 0, 0, 0);
        }

        float pw[8][4];
#pragma unroll
        for (int f = 0; f < 8; ++f)
#pragma unroll
            for (int r = 0; r < 4; ++r) pw[f][r] = sa[f][r] * 0.125f;
        float nm[4], fac[4];
#pragma unroll
        for (int r = 0; r < 4; ++r) {
            float m = pw[0][r];
#pragma unroll
            for (int f = 1; f < 8; ++f) m = fmaxf(m, pw[f][r]);
            m = fmaxf(m, __shfl_xor(m, 1));
            m = fmaxf(m, __shfl_xor(m, 2));
            m = fmaxf(m, __shfl_xor(m, 4));
            m = fmaxf(m, __shfl_xor(m, 8));
            nm[r] = fmaxf(mrun[r], m);
            fac[r] = __expf(mrun[r] - nm[r]);
            mrun[r] = nm[r];
        }
#pragma unroll
        for (int r = 0; r < 4; ++r) {
            float s = 0.f;
#pragma unroll
            for (int f = 0; f < 8; ++f) { float e = __expf(pw[f][r] - nm[r]); pw[f][r] = e; s += e; }
            s += __shfl_xor(s, 1); s += __shfl_xor(s, 2);
            s += __shfl_xor(s, 4); s += __shfl_xor(s, 8);
            lrun[r] = lrun[r] * fac[r] + s;
#pragma unroll
            for (int nf = 0; nf < 4; ++nf) o_acc[nf][r] *= fac[r];
        }

#pragma unroll
        for (int f = 0; f < 8; ++f)
#pragma unroll
            for (int r = 0; r < 4; ++r) {
                int qr = g * 4 + r, col = ls + 16 * f;
                *(unsigned short*)(pbase + ((qr * 256 + col * 2) ^ ((qr & 7) << 4))) = f2bf(pw[f][r]);
            }

#pragma unroll
        for (int ks = 0; ks < 4; ++ks) {
            bf16x8 pa = *(const bf16x8*)(pbase + ((ls * 256 + ks * 64 + g * 16) ^ ((ls & 7) << 4)));
#pragma unroll
            for (int nf = 0; nf < 4; ++nf) {
                int d = nf * 16 + ls;
                bf16x8 bv = *(const bf16x8*)((char*)Vlds + ((d * 256 + ks * 64 + g * 16) ^ ((d & 7) << 4)));
                o_acc[nf] = __builtin_amdgcn_mfma_f32_16x16x32_bf16(pa, bv, o_acc[nf], 0, 0, 0);
            }
        }
    }

    float inv[4];
#pragma unroll
    for (int r = 0; r < 4; ++r) inv[r] = 1.f / lrun[r];
#pragma unroll
    for (int nf = 0; nf < 4; ++nf)
#pragma unroll
        for (int r = 0; r < 4; ++r) {
            long row = bb * T_ + q0 + wv * 16 + g * 4 + r;
            outg[row * D_ + hh * 64 + nf * 16 + ls] = f2bf(o_acc[nf][r] * inv[r]);
        }
}

// ---------------- BatchNorm over tokens (deterministic two-stage) ----------------
__global__ __launch_bounds__(256)
void bn_part(const float* __restrict__ qf, float* __restrict__ pS, float* __restrict__ pSS) {
    int c = blockIdx.y * 256 + threadIdx.x;
    int r0 = blockIdx.x * 256;
    float s = 0.f, ss = 0.f;
    for (int r = 0; r < 256; ++r) {
        float v = qf[(long)(r0 + r) * DQ_ + c];
        s += v; ss += v * v;
    }
    pS[blockIdx.x * DQ_ + c] = s;
    pSS[blockIdx.x * DQ_ + c] = ss;
}

__global__ __launch_bounds__(256)
void bn_fin(const float* __restrict__ pS, const float* __restrict__ pSS,
            float* __restrict__ mu, float* __restrict__ rs) {
    int c = blockIdx.x * 256 + threadIdx.x;
    float s = 0.f, ss = 0.f;
#pragma unroll
    for (int i = 0; i < 8; ++i) { s += pS[i * DQ_ + c]; ss += pSS[i * DQ_ + c]; }
    float m = s * (1.f / NT);
    float var = ss * (1.f / NT) - m * m;
    mu[c] = m;
    rs[c] = rsqrtf(var + 1e-5f);
}

__global__ __launch_bounds__(256)
void qn_kernel(const float* __restrict__ qf, const float* __restrict__ mu,
               const float* __restrict__ rs, const float* __restrict__ g,
               const float* __restrict__ b, unsigned short* __restrict__ qn) {
    int i = blockIdx.x * 256 + threadIdx.x;
    int c = i & (DQ_ - 1);
    qn[i] = f2bf((qf[i] - mu[c]) * rs[c] * g[c] + b[c]);
}

// ---------------- fused top-k: 2 waves per task (parallel halves) ----------------
// block 256 = 2 tasks x 2 waves; wave (slot,half) extracts top-32 of its half,
// then even waves combine the 119-candidate frontier.
__global__ __launch_bounds__(256)
void topk_kernel(const float* __restrict__ dots, float* __restrict__ fs, int* __restrict__ vi) {
    static const unsigned short tab[128] = {
        0,1,2,3,4,5,6,7,8,9,10,11,12,13,14,15,16,17,18,19,20,21,22,23,24,25,26,27,28,29,30,31,
        32,33,34,35,36,37,38,39,40,41,42,43,44,45,46,47,
        64,65,66,67,68,69,70,71,72,73,
        96,97,98,99,100,101,102,103,
        128,129,130,131,132,133,
        160,161,162,163,164,
        192,193,194,195,
        224,225,226,227,
        256,257,258,
        288,289,290,
        320,321, 352,353, 384,385, 416,417, 448,449, 480,481,
        512,544,576,608,640,672,704,736,768,800,832,864,896,928,960,992,
        0xFFFF,0xFFFF,0xFFFF,0xFFFF,0xFFFF,0xFFFF,0xFFFF,0xFFFF,0xFFFF
    };
    __shared__ float sv[2][64];
    __shared__ int   sidx[2][64];
    int tid = threadIdx.x, wv = tid >> 6, lane = tid & 63;
    int slot = wv >> 1, half = wv & 1;
    long task = (long)blockIdx.x * 2 + slot;
    const float* d = dots + (task >> 2) * 2048 + (task & 3) * 512 + half * 256;

    float v0 = d[lane], v1 = d[lane + 64], v2 = d[lane + 128], v3 = d[lane + 192];
#pragma unroll 1
    for (int t = 0; t < 32; ++t) {
        float bm = v0; int ba = 0;
        if (v1 > bm) { bm = v1; ba = 1; }
        if (v2 > bm) { bm = v2; ba = 2; }
        if (v3 > bm) { bm = v3; ba = 3; }
        float wm = bm;
#pragma unroll
        for (int o = 32; o >= 1; o >>= 1) wm = fmaxf(wm, __shfl_xor(wm, o));
        unsigned long long msk = __ballot(bm == wm);
        int owner = (int)__builtin_ctzll(msk);
        if (lane == owner) {
            sv[slot][half * 32 + t] = wm;
            sidx[slot][half * 32 + t] = ba * 64 + lane;
            if (ba == 0) v0 = -1e30f;
            else if (ba == 1) v1 = -1e30f;
            else if (ba == 2) v2 = -1e30f;
            else v3 = -1e30f;
        }
    }
    __syncthreads();
    if (half) return;

    unsigned short t0 = tab[lane], t1 = tab[lane + 64];
    float c0 = -1e30f, c1 = -1e30f;
    int id0 = 0, id1 = 0;
    {
        int i = t0 >> 5, j = t0 & 31;
        c0 = sv[slot][i] + sv[slot][32 + j];
        id0 = sidx[slot][i] * NK_ + sidx[slot][32 + j];
    }
    if (t1 != 0xFFFF) {
        int i = t1 >> 5, j = t1 & 31;
        c1 = sv[slot][i] + sv[slot][32 + j];
        id1 = sidx[slot][i] * NK_ + sidx[slot][32 + j];
    }

    float* fo = fs + task * 32;
    int*   vo = vi + task * 32;
#pragma unroll 1
    for (int t = 0; t < 32; ++t) {
        float bm = c0; int sel = 0;
        if (c1 > bm) { bm = c1; sel = 1; }
        float wm = bm;
#pragma unroll
        for (int o = 32; o >= 1; o >>= 1) wm = fmaxf(wm, __shfl_xor(wm, o));
        unsigned long long msk = __ballot(bm == wm);
        int owner = (int)__builtin_ctzll(msk);
        if (lane == owner) {
            fo[t] = wm;
            vo[t] = sel ? id1 : id0;
            if (sel) c1 = -1e30f; else c0 = -1e30f;
        }
    }
}

// ---------------- softmax + gather(bf16 table) + residual ----------------
__global__ __launch_bounds__(384)
void pkm_out_bf16(const float* __restrict__ fs, const int* __restrict__ vi,
                  const unsigned short* __restrict__ valsb, const float* __restrict__ x1,
                  float* __restrict__ outp) {
    int n = blockIdx.x, tid = threadIdx.x;
    __shared__ float w[128];
    __shared__ int   rows[128];
    __shared__ float red[3 * 768];
    if (tid < 128) {
        float e = fs[(long)n * 128 + tid];
        rows[tid] = vi[(long)n * 128 + tid];
        float m = e;
#pragma unroll
        for (int o = 16; o >= 1; o >>= 1) m = fmaxf(m, __shfl_xor(m, o));
        float ex = __expf(e - m);
        float s = ex;
#pragma unroll
        for (int o = 16; o >= 1; o >>= 1) s += __shfl_xor(s, o);
        w[tid] = ex / s;
    }
    __syncthreads();
    int slot = tid / 96, chunk = tid % 96;
    float a0=0.f,a1=0.f,a2=0.f,a3=0.f,a4=0.f,a5=0.f,a6=0.f,a7=0.f;
#pragma unroll 4
    for (int e = 0; e < 32; ++e) {
        int er = e * 4 + slot;
        float wgt = w[er];
        long ro = (long)rows[er] * D_;
        bf16x8 v = *(const bf16x8*)(valsb + ro + chunk * 8);
        a0 += wgt * bf2f((unsigned short)v[0]); a1 += wgt * bf2f((unsigned short)v[1]);
        a2 += wgt * bf2f((unsigned short)v[2]); a3 += wgt * bf2f((unsigned short)v[3]);
        a4 += wgt * bf2f((unsigned short)v[4]); a5 += wgt * bf2f((unsigned short)v[5]);
        a6 += wgt * bf2f((unsigned short)v[6]); a7 += wgt * bf2f((unsigned short)v[7]);
    }
    if (slot > 0) {
        float* rp = &red[(slot - 1) * 768 + chunk * 8];
        rp[0]=a0; rp[1]=a1; rp[2]=a2; rp[3]=a3; rp[4]=a4; rp[5]=a5; rp[6]=a6; rp[7]=a7;
    }
    __syncthreads();
    if (slot == 0) {
        long o = (long)n * D_ + chunk * 8;
        const float* r0 = &red[chunk * 8];
        const float* r1 = &red[768 + chunk * 8];
        const float* r2 = &red[1536 + chunk * 8];
        f32x4 xa = *(const f32x4*)(x1 + o);
        f32x4 xb = *(const f32x4*)(x1 + o + 4);
        f32x4 o1 = { a0 + r0[0] + r1[0] + r2[0] + xa[0], a1 + r0[1] + r1[1] + r2[1] + xa[1],
                     a2 + r0[2] + r1[2] + r2[2] + xa[2], a3 + r0[3] + r1[3] + r2[3] + xa[3] };
        f32x4 o2 = { a4 + r0[4] + r1[4] + r2[4] + xb[0], a5 + r0[5] + r1[5] + r2[5] + xb[1],
                     a6 + r0[6] + r1[6] + r2[6] + xb[2], a7 + r0[7] + r1[7] + r2[7] + xb[3] };
        *(f32x4*)(outp + o) = o1;
        *(f32x4*)(outp + o + 4) = o2;
    }
}

// ---------------- fallback: f32-table gather ----------------
__global__ __launch_bounds__(384)
void pkm_out_f32(const float* __restrict__ fs, const int* __restrict__ vi,
                 const float* __restrict__ values, const float* __restrict__ x1,
                 float* __restrict__ outp) {
    int n = blockIdx.x, tid = threadIdx.x;
    __shared__ float w[128];
    __shared__ int   rows[128];
    __shared__ float red[768];
    if (tid < 128) {
        float e = fs[(long)n * 128 + tid];
        rows[tid] = vi[(long)n * 128 + tid];
        float m = e;
#pragma unroll
        for (int o = 16; o >= 1; o >>= 1) m = fmaxf(m, __shfl_xor(m, o));
        float ex = __expf(e - m);
        float s = ex;
#pragma unroll
        for (int o = 16; o >= 1; o >>= 1) s += __shfl_xor(s, o);
        w[tid] = ex / s;
    }
    __syncthreads();
    int slot = tid / 192, chunk = tid % 192;
    float a0 = 0.f, a1 = 0.f, a2 = 0.f, a3 = 0.f;
#pragma unroll 4
    for (int e = 0; e < 64; ++e) {
        int er = e * 2 + slot;
        float wgt = w[er];
        long ro = (long)rows[er] * D_;
        f32x4 v = *(const f32x4*)(values + ro + chunk * 4);
        a0 += wgt * v[0]; a1 += wgt * v[1]; a2 += wgt * v[2]; a3 += wgt * v[3];
    }
    if (slot == 1) {
        f32x4 t = {a0, a1, a2, a3};
        *(f32x4*)&red[chunk * 4] = t;
    }
    __syncthreads();
    if (slot == 0) {
        f32x4 o = *(const f32x4*)&red[chunk * 4];
        f32x4 xr = *(const f32x4*)(x1 + (long)n * D_ + chunk * 4);
        o[0] += a0 + xr[0]; o[1] += a1 + xr[1]; o[2] += a2 + xr[2]; o[3] += a3 + xr[3];
        *(f32x4*)(outp + (long)n * D_ + chunk * 4) = o;
    }
}

extern "C" void kernel_launch(void* const* d_in, const int* in_sizes, int n_in,
                              void* d_out, int out_size, void* d_ws, size_t ws_size,
                              hipStream_t stream) {
    const float* x    = (const float*)d_in[0];
    const float* wq   = (const float*)d_in[1];
    const float* bq   = (const float*)d_in[2];
    const float* wk   = (const float*)d_in[3];
    const float* bk   = (const float*)d_in[4];
    const float* wv   = (const float*)d_in[5];
    const float* bv   = (const float*)d_in[6];
    const float* wo   = (const float*)d_in[7];
    const float* bo   = (const float*)d_in[8];
    const float* ln1g = (const float*)d_in[9];
    const float* ln1b = (const float*)d_in[10];
    const float* ln2g = (const float*)d_in[11];
    const float* ln2b = (const float*)d_in[12];
    const float* pwq  = (const float*)d_in[13];
    const float* bng  = (const float*)d_in[14];
    const float* bnb  = (const float*)d_in[15];
    const float* keys = (const float*)d_in[16];
    const float* vals = (const float*)d_in[17];
    float* out = (float*)d_out;

    char* p = (char*)d_ws;
    auto alloc = [&](size_t bytes) -> char* {
        char* r = p; p += (bytes + 255) & ~(size_t)255; return r;
    };
    unsigned short* wqkvT = (unsigned short*)alloc((size_t)3 * D_ * D_ * 2);
    unsigned short* woT   = (unsigned short*)alloc((size_t)D_ * D_ * 2);
    unsigned short* pwqT  = (unsigned short*)alloc((size_t)D_ * DQ_ * 2);
    unsigned short* keyB  = (unsigned short*)alloc((size_t)PH_ * NK_ * 2 * DHK_ * 2);
    unsigned short* h1    = (unsigned short*)alloc((size_t)NT * D_ * 2);
    unsigned short* qkvB  = (unsigned short*)alloc((size_t)NT * QKVLD * 2);
    unsigned short* aout  = (unsigned short*)alloc((size_t)NT * D_ * 2);
    float* x1             = (float*)alloc((size_t)NT * D_ * 4);
    unsigned short* h2    = (unsigned short*)alloc((size_t)NT * D_ * 2);
    float* qf             = (float*)alloc((size_t)NT * DQ_ * 4);
    float* pS             = (float*)alloc((size_t)8 * DQ_ * 4);
    float* pSS            = (float*)alloc((size_t)8 * DQ_ * 4);
    float* mu             = (float*)alloc((size_t)DQ_ * 4);
    float* rs             = (float*)alloc((size_t)DQ_ * 4);
    unsigned short* qnB   = (unsigned short*)alloc((size_t)NT * DQ_ * 2);
    float* dots           = (float*)alloc((size_t)NT * 2048 * 4);
    float* fsb            = (float*)alloc((size_t)NT * PH_ * 32 * 4);
    int*   vib            = (int*)alloc((size_t)NT * PH_ * 32 * 4);

    // bf16 values table if workspace allows (~100.7 MB more)
    size_t used = (size_t)(p - (char*)d_ws);
    size_t vbytes = (size_t)NK_ * NK_ * D_ * 2;
    bool useBf = (used + vbytes + 256) <= ws_size;
    unsigned short* valsb = nullptr;
    if (useBf) valsb = (unsigned short*)alloc(vbytes);

    // weight prep
    transpose_kernel<<<dim3(24, 32, 5), dim3(32, 8), 0, stream>>>(wq, wk, wv, wo, pwq, wqkvT, woT, pwqT);
    conv_kernel<<<(PH_ * NK_ * 2 * DHK_) / 256, 256, 0, stream>>>(keys, keyB, PH_ * NK_ * 2 * DHK_);

    // LN1
    ln_kernel<<<NT, 256, 0, stream>>>(x, ln1g, ln1b, h1);
    // merged QKV GEMM -> qkvB; hosts first half of the values-table conversion
    gemm_kernel<<<dim3(32, useBf ? 52 : 36), 256, 0, stream>>>(
        h1, D_, wqkvT, D_, bq, bk, bv, nullptr, nullptr, qkvB, QKVLD, D_, 2,
        useBf ? vals : nullptr, valsb, 0L, 36);
    // attention (MFMA flash)
    attn_mfma_kernel<<<dim3(B_ * H_, T_ / 64), 256, 0, stream>>>(qkvB, aout);
    // output projection + residual
    gemm_kernel<<<dim3(32, 12), 256, 0, stream>>>(
        aout, D_, woT, D_, bo, nullptr, nullptr, x, x1, nullptr, D_, D_, 0,
        nullptr, nullptr, 0L, 0);
    // LN2 + PKM query GEMM; hosts second half of the values-table conversion
    ln_kernel<<<NT, 256, 0, stream>>>(x1, ln2g, ln2b, h2);
    gemm_kernel<<<dim3(32, useBf ? 32 : 16), 256, 0, stream>>>(
        h2, D_, pwqT, D_, nullptr, nullptr, nullptr, nullptr, qf, nullptr, DQ_, D_, 0,
        useBf ? vals : nullptr, valsb, CVHALF, 16);
    // BatchNorm
    bn_part<<<dim3(8, 4), 256, 0, stream>>>(qf, pS, pSS);
    bn_fin<<<4, 256, 0, stream>>>(pS, pSS, mu, rs);
    qn_kernel<<<(NT * DQ_) / 256, 256, 0, stream>>>(qf, mu, rs, bng, bnb, qnB);
    // dots: 8 batched GEMMs via blockIdx.z
    gemm_kernel<<<dim3(32, 4, 8), 256, 0, stream>>>(
        qnB, DQ_, keyB, 256, nullptr, nullptr, nullptr, nullptr, dots, nullptr, 2048, DHK_, 1,
        nullptr, nullptr, 0L, 0);
    // fused top-k (2 waves per task)
    topk_kernel<<<(NT * PH_) / 2, 256, 0, stream>>>(dots, fsb, vib);
    // softmax + gather + residual
    if (useBf)
        pkm_out_bf16<<<NT, 384, 0, stream>>>(fsb, vib, valsb, x1, out);
    else
        pkm_out_f32<<<NT, 384, 0, stream>>>(fsb, vib, vals, x1, out);
}